// Round 4
// baseline (500.489 us; speedup 1.0000x reference)
//
#include <hip/hip_runtime.h>

#define N_NODES 20000
#define N_EDGES 640000

typedef _Float16 h2v   __attribute__((ext_vector_type(2)));
typedef _Float16 h16x8 __attribute__((ext_vector_type(8)));
typedef float    f32x4v __attribute__((ext_vector_type(4)));
typedef unsigned u32x4v __attribute__((ext_vector_type(4)));

__device__ __forceinline__ unsigned packh2(float a, float b){
    h2v v; v.x = (_Float16)a; v.y = (_Float16)b;
    return __builtin_bit_cast(unsigned, v);
}

// ---------------- k0: zero flags + histogram counters ----------------
__global__ void k0_zero(float4* __restrict__ p, int n4){
    int i = blockIdx.x*blockDim.x + threadIdx.x;
    int stride = gridDim.x*blockDim.x;
    float4 z; z.x=0.f; z.y=0.f; z.z=0.f; z.w=0.f;
    for (; i<n4; i+=stride) p[i] = z;
}

// ---------------- kD: detect int32 vs int64 index buffers ----------------
__global__ void kD_detect(const int* __restrict__ eidx_w, const int* __restrict__ ety_w,
                          int* __restrict__ flags){
    int i = blockIdx.x*blockDim.x + threadIdx.x;
    int stride = gridDim.x*blockDim.x;
    int a0 = 0, a1 = 0;
    for (int w = 2*i+1; w < 2*N_EDGES; w += 2*stride) a0 |= eidx_w[w];
    for (int w = 2*i+1; w < N_EDGES;   w += 2*stride) a1 |= ety_w[w];
    if (a0) atomicOr(&flags[0], 1);
    if (a1) atomicOr(&flags[1], 1);
}

// ---------------- kN: normalize indices + dst histogram + per-edge rank ----------------
__global__ void kN_norm(const int* __restrict__ eidx_w, const int* __restrict__ ety_w,
                        const int* __restrict__ flags,
                        int* __restrict__ dst, int* __restrict__ srcty,
                        int* __restrict__ rankA, int* __restrict__ cnt){
    int i = blockIdx.x*blockDim.x + threadIdx.x;
    int stride = gridDim.x*blockDim.x;
    const bool e32 = (flags[0] != 0);
    const bool t32 = (flags[1] != 0);
    for (int e = i; e < N_EDGES; e += stride){
        int s, d, t;
        if (e32){ s = eidx_w[e];   d = eidx_w[N_EDGES + e]; }
        else    { s = eidx_w[2*e]; d = eidx_w[2*N_EDGES + 2*e]; }
        t = t32 ? ety_w[e] : ety_w[2*e];
        s = min(max(s, 0), N_NODES-1);
        d = min(max(d, 0), N_NODES-1);
        t = min(max(t, 0), 15);
        dst[e] = d; srcty[e] = s | (t << 20);
        rankA[e] = atomicAdd(&cnt[d], 1);   // within-node rank: free CSR slot
    }
}

// ---------------- kS: exclusive scan (4 elems/thread) -> row_ptr ----------------
__global__ __launch_bounds__(1024) void kS_scan(const int* __restrict__ cnt,
                                                int* __restrict__ row_ptr){
    __shared__ int sW[16];
    __shared__ int sWS[16];
    __shared__ int sbase;
    const int t = threadIdx.x, lane = t & 63, wv = t >> 6;
    if (t==0) sbase = 0;
    __syncthreads();
    for (int base=0; base<N_NODES; base+=4096){
        const int idx0 = base + t*4;
        int v0 = (idx0  <N_NODES) ? cnt[idx0  ] : 0;
        int v1 = (idx0+1<N_NODES) ? cnt[idx0+1] : 0;
        int v2 = (idx0+2<N_NODES) ? cnt[idx0+2] : 0;
        int v3 = (idx0+3<N_NODES) ? cnt[idx0+3] : 0;
        int p1 = v0+v1, p2 = p1+v2, tot = p2+v3;
        int xs = tot;
        #pragma unroll
        for (int off=1; off<64; off<<=1){
            int y = __shfl_up(xs, off, 64);
            if (lane >= off) xs += y;
        }
        if (lane==63) sW[wv] = xs;
        __syncthreads();
        if (t < 16){
            int wvv = sW[t], ws = wvv;
            #pragma unroll
            for (int off=1; off<16; off<<=1){
                int y = __shfl_up(ws, off, 16);
                if ((t&15) >= off) ws += y;
            }
            sWS[t] = ws - wvv;
        }
        __syncthreads();
        int ex = sbase + sWS[wv] + xs - tot;
        if (idx0  <N_NODES){ row_ptr[idx0  ]=ex;    }
        if (idx0+1<N_NODES){ row_ptr[idx0+1]=ex+v0; }
        if (idx0+2<N_NODES){ row_ptr[idx0+2]=ex+p1; }
        if (idx0+3<N_NODES){ row_ptr[idx0+3]=ex+p2; }
        __syncthreads();
        if (t==0) sbase += sWS[15] + sW[15];
        __syncthreads();
    }
    if (t==0) row_ptr[N_NODES] = sbase;
}

// ---------------- kPre: fused Mt/ATw (block 16) + Tw (blocks 0..15) ----------------
__global__ __launch_bounds__(256) void kPre(const float* __restrict__ gat_edge_W,
                                            const float* __restrict__ a_edge,
                                            const float* __restrict__ gat_emb,
                                            const float* __restrict__ gine_emb,
                                            const float* __restrict__ gine_edge_W,
                                            const float* __restrict__ gine_edge_b,
                                            float* __restrict__ Mt, float* __restrict__ ATw,
                                            float* __restrict__ Tw){
    const int t = threadIdx.x;
    if (blockIdx.x < 16){
        if (t < 128){
            const int tyv = blockIdx.x;
            float acc = gine_edge_b[t];
            #pragma unroll
            for (int d=0;d<32;d++) acc += gine_emb[tyv*32+d]*gine_edge_W[d*128+t];
            Tw[tyv*128+t] = acc;
        }
        return;
    }
    __shared__ float sM[32*8];
    const int d = t>>3, hh = t&7;
    float acc = 0.f;
    #pragma unroll
    for (int c=0;c<16;c++) acc += gat_edge_W[d*128 + hh*16 + c]*a_edge[hh*16 + c];
    sM[d*8+hh] = acc; Mt[hh*32 + d] = acc;
    __syncthreads();
    if (t < 128){
        int tyv = t>>3, h2 = t&7;
        float a = 0.f;
        #pragma unroll
        for (int dd=0;dd<32;dd++) a += gat_emb[tyv*32+dd]*sM[dd*8+h2];
        ATw[tyv*8+h2] = a;
    }
}

// ---------------- kW: pack W1/W2/comb_W into MFMA fragment-ordered f16 ----------------
__global__ __launch_bounds__(256) void kW_pack(
    const float* __restrict__ W1, const float* __restrict__ W2,
    const float* __restrict__ combW,
    unsigned* __restrict__ W1p, unsigned* __restrict__ W2p, unsigned* __restrict__ combp)
{
    const int tid = blockIdx.x*256 + threadIdx.x;
    const int chunk = tid >> 6;
    const int l = tid & 63;
    const int n = l & 15, g = l >> 4;
    const float* W; unsigned* P; int NCH, cbase;
    if (chunk < 32)      { W = W1;    P = W1p;   NCH = 128; cbase = chunk; }
    else if (chunk < 64) { W = W2;    P = W2p;   NCH = 128; cbase = chunk - 32; }
    else if (chunk < 192){ W = combW; P = combp; NCH = 256; cbase = chunk - 64; }
    else return;
    const int nblocks = NCH/16;
    const int kstep = cbase / nblocks, nblk = cbase % nblocks;
    const int k0 = kstep*32 + 8*g, col = nblk*16 + n;
    unsigned u0 = packh2(W[(size_t)(k0+0)*NCH + col], W[(size_t)(k0+1)*NCH + col]);
    unsigned u1 = packh2(W[(size_t)(k0+2)*NCH + col], W[(size_t)(k0+3)*NCH + col]);
    unsigned u2 = packh2(W[(size_t)(k0+4)*NCH + col], W[(size_t)(k0+5)*NCH + col]);
    unsigned u3 = packh2(W[(size_t)(k0+6)*NCH + col], W[(size_t)(k0+7)*NCH + col]);
    ((uint4*)P)[(size_t)cbase*64 + l] = make_uint4(u0,u1,u2,u3);
}

// ---------------- k1: h = x@gat_W (8 nodes/block), pack xhb (f16x2), a_s, a_d ----------------
__global__ __launch_bounds__(128) void k1_node_prep(
    const float* __restrict__ x, const float* __restrict__ gat_W,
    const float* __restrict__ a_src, const float* __restrict__ a_dst,
    unsigned* __restrict__ xhb, float* __restrict__ as_out, float* __restrict__ ad_out)
{
    __shared__ float sX[8][128];
    __shared__ float sH[128];
    const int t = threadIdx.x;
    const int base = blockIdx.x*8;
    const float4* xin = (const float4*)(x + (size_t)base*128);
    float4* sx4 = (float4*)&sX[0][0];
    for (int i=t;i<256;i+=128) sx4[i] = xin[i];
    __syncthreads();
    float acc[8] = {0,0,0,0,0,0,0,0};
    for (int k=0;k<128;k++){
        float w = gat_W[k*128 + t];
        #pragma unroll
        for (int nn=0;nn<8;nn++) acc[nn] += sX[nn][k]*w;
    }
    const float asv = a_src[t], advv = a_dst[t];
    #pragma unroll
    for (int nn=0;nn<8;nn++){
        const int n = base + nn;
        float vs = acc[nn]*asv, vd = acc[nn]*advv;
        #pragma unroll
        for (int off=8; off>=1; off>>=1){ vs += __shfl_xor(vs,off,16); vd += __shfl_xor(vd,off,16); }
        if ((t&15)==0){ as_out[n*8 + (t>>4)] = vs; ad_out[n*8 + (t>>4)] = vd; }
        __syncthreads();               // protect sH from previous nn's readers
        sH[t] = acc[nn];
        __syncthreads();
        if (t < 64){
            xhb[(size_t)n*128 + t] = packh2(sX[nn][2*t], sX[nn][2*t+1]);
        } else {
            int i = t - 64;
            xhb[(size_t)n*128 + 64 + i] = packh2(sH[2*i], sH[2*i+1]);
        }
    }
}

// ---------------- kCE: barrier-free, atomic-free edge precompute ----------------
// 8 lanes per edge (q=head). pos = row_ptr[d] + rank (precomputed in kN).
// 128B record: [attrs f16x32 | p f32x8 head-permuted [0,2,4,6,1,3,5,7] | sty x8].
__global__ __launch_bounds__(256) void kCE_edge(
    const float* __restrict__ eattr,
    const int* __restrict__ dstA, const int* __restrict__ styA,
    const int* __restrict__ rankA, const int* __restrict__ rowp,
    const float* __restrict__ a_s, const float* __restrict__ a_d,
    const float* __restrict__ Mt, const float* __restrict__ ATw,
    const float* __restrict__ gine_emb,
    unsigned* __restrict__ erec)
{
    const int t = threadIdx.x;
    const int q = t & 7;
    // preload this lane's 4-dim slice of all 8 head vectors (Mt is [8][32])
    float4 mtr[8];
    #pragma unroll
    for (int h=0;h<8;h++) mtr[h] = ((const float4*)Mt)[h*8 + q];

    const int e0 = (blockIdx.x*256 + t) >> 3;
    const int estride = (gridDim.x*256) >> 3;
    for (int e = e0; e < N_EDGES; e += estride){
        float4 f = ((const float4*)eattr)[(size_t)e*8 + q];
        const int d    = dstA[e];
        const int sty  = styA[e];
        const int pos  = rowp[d] + rankA[e];
        const int srcn = sty & 0xFFFFF;
        const int tyv  = ((unsigned)sty)>>20;

        // attrs: f16(eattr + gine_type_emb)
        const float4 ge = ((const float4*)gine_emb)[tyv*8 + q];
        ((uint2*)erec)[(size_t)pos*16 + q] =
            make_uint2(packh2(f.x+ge.x, f.y+ge.y), packh2(f.z+ge.z, f.w+ge.w));

        // per-lane partial dot for every head (32 FMA)
        float ph[8];
        #pragma unroll
        for (int h=0;h<8;h++)
            ph[h] = f.x*mtr[h].x + f.y*mtr[h].y + f.z*mtr[h].z + f.w*mtr[h].w;
        // 3-step reduce-scatter within the 8-lane group -> lane q holds head q's dot
        #pragma unroll
        for (int i=0;i<4;i++){
            float send = (q&1) ? ph[2*i] : ph[2*i+1];
            float recv = __shfl_xor(send, 1, 64);
            ph[i] = ((q&1) ? ph[2*i+1] : ph[2*i]) + recv;
        }
        #pragma unroll
        for (int i=0;i<2;i++){
            float send = (q&2) ? ph[2*i] : ph[2*i+1];
            float recv = __shfl_xor(send, 2, 64);
            ph[i] = ((q&2) ? ph[2*i+1] : ph[2*i]) + recv;
        }
        {
            float send = (q&4) ? ph[0] : ph[1];
            float recv = __shfl_xor(send, 4, 64);
            ph[0] = ((q&4) ? ph[1] : ph[0]) + recv;
        }

        float lg = a_s[srcn*8+q] + a_d[d*8+q] + ph[0] + ATw[tyv*8+q];
        lg = (lg>0.f) ? lg : 0.2f*lg;
        // permuted p slot: even heads first, then odd
        ((float*)erec)[(size_t)pos*32 + 16 + ((q&1)*4 + (q>>1))] = __expf(lg);
        ((int*)erec)[(size_t)pos*32 + 24 + q] = sty;   // fills rest of the 128B line
    }
}

// ---------------- k3: MFMA-based CSR gather, channel-pair columns ----------------
// Lane (lm = lane&15, g = lane>>4): A row = edge lm; per 32-channel chunk c,
// two MFMAs (even/odd W frags) give ep for channels (32c+2*lm, +1) of edges 4g+r.
// x/h gathers are aligned dwords (f16x2); p is one dwordx4 (permuted heads).
template<bool MASK>
__device__ __forceinline__ void gine_block16(
    int pos0, int rem, int lm, int g,
    const unsigned* __restrict__ xhb, const unsigned* __restrict__ erec,
    const h16x8* awe, const h16x8* awo, const float* be, const float* bo,
    float* accA0, float* accA1, float* accG0, float* accG1, float* ps)
{
    const int mc = MASK ? (lm < rem ? lm : rem - 1) : lm;
    u32x4v uu = ((const u32x4v*)erec)[(size_t)(pos0 + mc)*8 + g];
    h16x8 evf = __builtin_bit_cast(h16x8, uu);
    const int P = lm >> 3;

    const unsigned* xq[4];
    f32x4v pv[4];
    #pragma unroll
    for (int r=0;r<4;r++){
        const int er = 4*g + r;
        const int ec = MASK ? (er < rem ? er : rem - 1) : er;
        const int pe = pos0 + ec;
        const int srcn = ((const int*)erec)[(size_t)pe*32 + 24] & 0xFFFFF;
        xq[r] = xhb + (size_t)srcn*128;
        pv[r] = *(const f32x4v*)((const float*)erec + (size_t)pe*32 + 16 + P*4);
        if (MASK && er >= rem) pv[r] = (f32x4v){0.f,0.f,0.f,0.f};
    }
    #pragma unroll
    for (int r=0;r<4;r++){
        ps[0] += pv[r][0]; ps[1] += pv[r][1]; ps[2] += pv[r][2]; ps[3] += pv[r][3];
    }
    #pragma unroll
    for (int c=0;c<4;c++){
        f32x4v De = { be[c], be[c], be[c], be[c] };
        f32x4v Do = { bo[c], bo[c], bo[c], bo[c] };
        De = __builtin_amdgcn_mfma_f32_16x16x32_f16(evf, awe[c], De, 0, 0, 0);
        Do = __builtin_amdgcn_mfma_f32_16x16x32_f16(evf, awo[c], Do, 0, 0, 0);
        #pragma unroll
        for (int r=0;r<4;r++){
            const unsigned xw = xq[r][16*c + lm];
            const unsigned hw = xq[r][64 + 16*c + lm];
            h2v xv = __builtin_bit_cast(h2v, xw);
            h2v hv = __builtin_bit_cast(h2v, hw);
            float a0 = fmaxf(De[r] + (float)xv.x, 0.f);
            float a1 = fmaxf(Do[r] + (float)xv.y, 0.f);
            if (MASK && (4*g + r) >= rem){ a0 = 0.f; a1 = 0.f; }
            accA0[c] += a0; accA1[c] += a1;
            accG0[c] += pv[r][c]*(float)hv.x;
            accG1[c] += pv[r][c]*(float)hv.y;
        }
    }
}

__global__ __launch_bounds__(256) void k3_gather(
    const unsigned* __restrict__ xhb, const unsigned* __restrict__ erec,
    const int* __restrict__ row_ptr,
    const float* __restrict__ gine_b, const float* __restrict__ gine_W,
    float* __restrict__ agg, float* __restrict__ gacc)
{
    const int t = threadIdx.x;
    const int lane = t & 63;
    const int lm = lane & 15;
    const int g = lane >> 4;

    // B fragments: awe[c][j] = W[8g+j][32c+2*lm], awo: +1
    h16x8 awe[4], awo[4];
    #pragma unroll
    for (int c=0;c<4;c++){
        #pragma unroll
        for (int j=0;j<8;j++){
            awe[c][j] = (_Float16)gine_W[(8*g + j)*128 + 32*c + 2*lm];
            awo[c][j] = (_Float16)gine_W[(8*g + j)*128 + 32*c + 2*lm + 1];
        }
    }
    float be[4], bo[4];
    #pragma unroll
    for (int c=0;c<4;c++){ be[c] = gine_b[32*c + 2*lm]; bo[c] = gine_b[32*c + 2*lm + 1]; }

    const int nwaves = gridDim.x*4;
    for (int d = blockIdx.x*4 + (t>>6); d < N_NODES; d += nwaves){
        const int row = row_ptr[d], end = row_ptr[d+1];
        float accA0[4]={0,0,0,0}, accA1[4]={0,0,0,0};
        float accG0[4]={0,0,0,0}, accG1[4]={0,0,0,0};
        float ps[4]={0,0,0,0};
        const int deg = end - row;
        int pos0 = row;
        const int nfull = deg >> 4;
        for (int b=0;b<nfull;b++, pos0+=16)
            gine_block16<false>(pos0, 16, lm, g, xhb, erec, awe, awo, be, bo,
                                accA0, accA1, accG0, accG1, ps);
        const int rem = deg & 15;
        if (rem)
            gine_block16<true>(pos0, rem, lm, g, xhb, erec, awe, awo, be, bo,
                               accA0, accA1, accG0, accG1, ps);
        // reduce over the 4 edge-subgroups (lane bits 4-5)
        #pragma unroll
        for (int c=0;c<4;c++){
            accA0[c] += __shfl_xor(accA0[c], 16, 64); accA0[c] += __shfl_xor(accA0[c], 32, 64);
            accA1[c] += __shfl_xor(accA1[c], 16, 64); accA1[c] += __shfl_xor(accA1[c], 32, 64);
            accG0[c] += __shfl_xor(accG0[c], 16, 64); accG0[c] += __shfl_xor(accG0[c], 32, 64);
            accG1[c] += __shfl_xor(accG1[c], 16, 64); accG1[c] += __shfl_xor(accG1[c], 32, 64);
            ps[c]    += __shfl_xor(ps[c],    16, 64); ps[c]    += __shfl_xor(ps[c],    32, 64);
        }
        if (g == 0){
            #pragma unroll
            for (int c=0;c<4;c++){
                const float inv = 1.f/(ps[c] + 1e-16f);
                ((float2*)agg )[(size_t)d*64 + 16*c + lm] = make_float2(accA0[c], accA1[c]);
                ((float2*)gacc)[(size_t)d*64 + 16*c + lm] = make_float2(accG0[c]*inv, accG1[c]*inv);
            }
        }
    }
}

// ---------------- k4: MFMA final node kernel ----------------
#define K4N 32
__global__ __launch_bounds__(256) void k4_final(
    const float* __restrict__ x, const float* __restrict__ agg, const float* __restrict__ gacc,
    const float* __restrict__ gat_b, const float* __restrict__ eps_p,
    const unsigned* __restrict__ W1p, const float* __restrict__ b1,
    const unsigned* __restrict__ W2p, const float* __restrict__ gb2,
    const unsigned* __restrict__ combp, const float* __restrict__ comb_b,
    const float* __restrict__ ln_g, const float* __restrict__ ln_b,
    float* __restrict__ out)
{
    __shared__ _Float16 sHi[K4N][136];
    __shared__ _Float16 sLo[K4N][136];
    __shared__ _Float16 sCH[K4N][264];
    __shared__ float sRed[K4N][8];
    __shared__ float sMV[K4N][2];
    const int t = threadIdx.x;
    const int l = t & 63, wid = t >> 6;
    const int n = l & 15, g = l >> 4;
    const float epsv = 1.f + eps_p[0];
    const int base = blockIdx.x*K4N;

    for (int i = t; i < K4N*32; i += 256){
        const int node = i >> 5, c4 = i & 31;
        float4 xv = ((const float4*)x   )[(size_t)(base+node)*32 + c4];
        float4 av = ((const float4*)agg )[(size_t)(base+node)*32 + c4];
        float4 gv = ((const float4*)gacc)[(size_t)(base+node)*32 + c4];
        float4 bv = ((const float4*)gat_b)[c4];
        float h0 = epsv*xv.x + av.x, h1 = epsv*xv.y + av.y;
        float h2_ = epsv*xv.z + av.z, h3 = epsv*xv.w + av.w;
        _Float16 f0=(_Float16)h0, f1=(_Float16)h1, f2=(_Float16)h2_, f3=(_Float16)h3;
        h2v p01; p01.x=f0; p01.y=f1;  h2v p23; p23.x=f2; p23.y=f3;
        *(uint2*)&sHi[node][c4*4] = make_uint2(__builtin_bit_cast(unsigned,p01),
                                               __builtin_bit_cast(unsigned,p23));
        h2v q01, q23;
        q01.x=(_Float16)(h0-(float)f0); q01.y=(_Float16)(h1-(float)f1);
        q23.x=(_Float16)(h2_-(float)f2); q23.y=(_Float16)(h3-(float)f3);
        *(uint2*)&sLo[node][c4*4] = make_uint2(__builtin_bit_cast(unsigned,q01),
                                               __builtin_bit_cast(unsigned,q23));
        *(uint2*)&sCH[node][c4*4] = make_uint2(packh2(gv.x+bv.x, gv.y+bv.y),
                                               packh2(gv.z+bv.z, gv.w+bv.w));
    }
    __syncthreads();

    f32x4v acc1[2][2];
    #pragma unroll
    for (int mt=0;mt<2;mt++)
        #pragma unroll
        for (int nt=0;nt<2;nt++){
            float b = b1[32*wid + 16*nt + n];
            acc1[mt][nt] = (f32x4v){b,b,b,b};
        }
    #pragma unroll
    for (int ks=0;ks<4;ks++){
        h16x8 bfr[2];
        #pragma unroll
        for (int nt=0;nt<2;nt++){
            uint4 u = ((const uint4*)W1p)[(size_t)((ks*8 + 2*wid + nt)*64 + l)];
            bfr[nt] = __builtin_bit_cast(h16x8, u);
        }
        #pragma unroll
        for (int mt=0;mt<2;mt++){
            const int row = 16*mt + n;
            h16x8 ahi = *(const h16x8*)&sHi[row][8*g + 32*ks];
            h16x8 alo = *(const h16x8*)&sLo[row][8*g + 32*ks];
            #pragma unroll
            for (int nt=0;nt<2;nt++){
                acc1[mt][nt] = __builtin_amdgcn_mfma_f32_16x16x32_f16(ahi, bfr[nt], acc1[mt][nt], 0,0,0);
                acc1[mt][nt] = __builtin_amdgcn_mfma_f32_16x16x32_f16(alo, bfr[nt], acc1[mt][nt], 0,0,0);
            }
        }
    }
    __syncthreads();
    #pragma unroll
    for (int mt=0;mt<2;mt++)
        #pragma unroll
        for (int nt=0;nt<2;nt++)
            #pragma unroll
            for (int r=0;r<4;r++)
                sHi[16*mt + 4*g + r][32*wid + 16*nt + n] = (_Float16)fmaxf(acc1[mt][nt][r], 0.f);
    __syncthreads();

    f32x4v acc2[2][2];
    #pragma unroll
    for (int mt=0;mt<2;mt++)
        #pragma unroll
        for (int nt=0;nt<2;nt++){
            float b = gb2[32*wid + 16*nt + n];
            acc2[mt][nt] = (f32x4v){b,b,b,b};
        }
    #pragma unroll
    for (int ks=0;ks<4;ks++){
        h16x8 bfr[2];
        #pragma unroll
        for (int nt=0;nt<2;nt++){
            uint4 u = ((const uint4*)W2p)[(size_t)((ks*8 + 2*wid + nt)*64 + l)];
            bfr[nt] = __builtin_bit_cast(h16x8, u);
        }
        #pragma unroll
        for (int mt=0;mt<2;mt++){
            h16x8 a = *(const h16x8*)&sHi[16*mt + n][8*g + 32*ks];
            #pragma unroll
            for (int nt=0;nt<2;nt++)
                acc2[mt][nt] = __builtin_amdgcn_mfma_f32_16x16x32_f16(a, bfr[nt], acc2[mt][nt], 0,0,0);
        }
    }
    #pragma unroll
    for (int mt=0;mt<2;mt++)
        #pragma unroll
        for (int nt=0;nt<2;nt++)
            #pragma unroll
            for (int r=0;r<4;r++)
                sCH[16*mt + 4*g + r][128 + 32*wid + 16*nt + n] = (_Float16)acc2[mt][nt][r];
    __syncthreads();

    f32x4v accC[2][4];
    #pragma unroll
    for (int mt=0;mt<2;mt++)
        #pragma unroll
        for (int nt=0;nt<4;nt++){
            float b = comb_b[64*wid + 16*nt + n];
            accC[mt][nt] = (f32x4v){b,b,b,b};
        }
    #pragma unroll
    for (int ks=0;ks<8;ks++){
        h16x8 bfr[4];
        #pragma unroll
        for (int nt=0;nt<4;nt++){
            uint4 u = ((const uint4*)combp)[(size_t)((ks*16 + 4*wid + nt)*64 + l)];
            bfr[nt] = __builtin_bit_cast(h16x8, u);
        }
        #pragma unroll
        for (int mt=0;mt<2;mt++){
            h16x8 a = *(const h16x8*)&sCH[16*mt + n][8*g + 32*ks];
            #pragma unroll
            for (int nt=0;nt<4;nt++)
                accC[mt][nt] = __builtin_amdgcn_mfma_f32_16x16x32_f16(a, bfr[nt], accC[mt][nt], 0,0,0);
        }
    }

    #pragma unroll
    for (int mt=0;mt<2;mt++)
        #pragma unroll
        for (int r=0;r<4;r++){
            float s1=0.f, s2=0.f;
            #pragma unroll
            for (int nt=0;nt<4;nt++){ float z = accC[mt][nt][r]; s1 += z; s2 += z*z; }
            #pragma unroll
            for (int off=1; off<16; off<<=1){ s1 += __shfl_xor(s1,off,16); s2 += __shfl_xor(s2,off,16); }
            if (n==0){
                sRed[16*mt + 4*g + r][2*wid  ] = s1;
                sRed[16*mt + 4*g + r][2*wid+1] = s2;
            }
        }
    __syncthreads();
    if (t < K4N){
        float a1 = sRed[t][0]+sRed[t][2]+sRed[t][4]+sRed[t][6];
        float a2 = sRed[t][1]+sRed[t][3]+sRed[t][5]+sRed[t][7];
        float mu = a1*(1.f/256.f);
        float var = a2*(1.f/256.f) - mu*mu;
        sMV[t][0] = mu; sMV[t][1] = rsqrtf(var + 1e-5f);
    }
    __syncthreads();
    float lg[4], lb[4];
    #pragma unroll
    for (int nt=0;nt<4;nt++){ int ch = 64*wid + 16*nt + n; lg[nt]=ln_g[ch]; lb[nt]=ln_b[ch]; }
    #pragma unroll
    for (int mt=0;mt<2;mt++)
        #pragma unroll
        for (int r=0;r<4;r++){
            const int row = 16*mt + 4*g + r;
            const float mu = sMV[row][0], rs = sMV[row][1];
            #pragma unroll
            for (int nt=0;nt<4;nt++){
                const int ch = 64*wid + 16*nt + n;
                float zz = accC[mt][nt][r];
                out[(size_t)(base+row)*256 + ch] = fmaxf((zz-mu)*rs*lg[nt] + lb[nt], 0.f);
            }
        }
}

extern "C" void kernel_launch(void* const* d_in, const int* in_sizes, int n_in,
                              void* d_out, int out_size, void* d_ws, size_t ws_size,
                              hipStream_t stream)
{
    (void)in_sizes; (void)n_in; (void)out_size; (void)ws_size;
    const float* x           = (const float*)d_in[0];
    const int*   eidx_w      = (const int*)  d_in[1];
    const float* eattr       = (const float*)d_in[2];
    const int*   ety_w       = (const int*)  d_in[3];
    const float* gat_W       = (const float*)d_in[4];
    const float* gat_b       = (const float*)d_in[5];
    const float* gat_edge_W  = (const float*)d_in[6];
    const float* a_src       = (const float*)d_in[7];
    const float* a_dst       = (const float*)d_in[8];
    const float* a_edge      = (const float*)d_in[9];
    const float* gat_emb     = (const float*)d_in[10];
    const float* gine_emb    = (const float*)d_in[11];
    const float* gine_edge_W = (const float*)d_in[12];
    const float* gine_edge_b = (const float*)d_in[13];
    const float* gine_eps    = (const float*)d_in[14];
    const float* W1          = (const float*)d_in[15];
    const float* b1          = (const float*)d_in[16];
    const float* W2          = (const float*)d_in[17];
    const float* gb2         = (const float*)d_in[18];
    const float* comb_W      = (const float*)d_in[19];
    const float* comb_b      = (const float*)d_in[20];
    const float* ln_g        = (const float*)d_in[21];
    const float* ln_b        = (const float*)d_in[22];
    float* out = (float*)d_out;

    char* ws = (char*)d_ws;
    size_t off = 0;
    auto alloc = [&](size_t bytes)->void*{ void* p = ws + off; off += (bytes + 255)/256*256; return p; };
    size_t zero_start = off;
    int*      flags  = (int*)     alloc(256);
    int*      cnt    = (int*)     alloc((size_t)N_NODES*4);
    size_t zero_bytes = off - zero_start;
    int*      dstA   = (int*)     alloc((size_t)N_EDGES*4);
    int*      styA   = (int*)     alloc((size_t)N_EDGES*4);
    int*      rankA  = (int*)     alloc((size_t)N_EDGES*4);
    int*      rowp   = (int*)     alloc((size_t)(N_NODES+1)*4);
    unsigned* erec   = (unsigned*)alloc((size_t)N_EDGES*128);
    unsigned* xhb    = (unsigned*)alloc((size_t)N_NODES*128*4);
    float*    a_s    = (float*)   alloc((size_t)N_NODES*8*4);
    float*    a_d    = (float*)   alloc((size_t)N_NODES*8*4);
    float*    Mt     = (float*)   alloc(32*8*4);
    float*    ATw    = (float*)   alloc(16*8*4);
    float*    Tw     = (float*)   alloc(16*128*4);
    float*    agg    = (float*)   alloc((size_t)N_NODES*128*4);
    float*    gacc   = (float*)   alloc((size_t)N_NODES*128*4);
    unsigned* W1p    = (unsigned*)alloc((size_t)32*1024);
    unsigned* W2p    = (unsigned*)alloc((size_t)32*1024);
    unsigned* combp  = (unsigned*)alloc((size_t)128*1024);

    int n4 = (int)(zero_bytes/16);
    k0_zero<<<(n4+255)/256, 256, 0, stream>>>((float4*)(ws + zero_start), n4);
    kD_detect<<<512, 256, 0, stream>>>(eidx_w, ety_w, flags);
    kN_norm<<<1024, 256, 0, stream>>>(eidx_w, ety_w, flags, dstA, styA, rankA, cnt);
    kS_scan<<<1, 1024, 0, stream>>>(cnt, rowp);

    kW_pack<<<48, 256, 0, stream>>>(W1, W2, comb_W, W1p, W2p, combp);
    kPre<<<17, 256, 0, stream>>>(gat_edge_W, a_edge, gat_emb, gine_emb,
                                 gine_edge_W, gine_edge_b, Mt, ATw, Tw);
    k1_node_prep<<<N_NODES/8, 128, 0, stream>>>(x, gat_W, a_src, a_dst, xhb, a_s, a_d);

    kCE_edge<<<2500, 256, 0, stream>>>(eattr, dstA, styA, rankA, rowp,
                                       a_s, a_d, Mt, ATw, gine_emb, erec);

    k3_gather<<<5000, 256, 0, stream>>>(xhb, erec, rowp,
                                        gine_edge_b, gine_edge_W, agg, gacc);

    k4_final<<<N_NODES/K4N, 256, 0, stream>>>(x, agg, gacc, gat_b, gine_eps,
                                              W1p, b1, W2p, gb2, combp, comb_b,
                                              ln_g, ln_b, out);
}

// Round 5
// 405.783 us; speedup vs baseline: 1.2334x; 1.2334x over previous
//
#include <hip/hip_runtime.h>

#define N_NODES 20000
#define N_EDGES 640000

typedef _Float16 h2v   __attribute__((ext_vector_type(2)));
typedef _Float16 h16x8 __attribute__((ext_vector_type(8)));
typedef float    f32x4v __attribute__((ext_vector_type(4)));
typedef unsigned u32x4v __attribute__((ext_vector_type(4)));

__device__ __forceinline__ unsigned packh2(float a, float b){
    h2v v; v.x = (_Float16)a; v.y = (_Float16)b;
    return __builtin_bit_cast(unsigned, v);
}

// ---------------- k0: zero flags + histogram counters ----------------
__global__ void k0_zero(float4* __restrict__ p, int n4){
    int i = blockIdx.x*blockDim.x + threadIdx.x;
    int stride = gridDim.x*blockDim.x;
    float4 z; z.x=0.f; z.y=0.f; z.z=0.f; z.w=0.f;
    for (; i<n4; i+=stride) p[i] = z;
}

// ---------------- kD: detect int32 vs int64 index buffers ----------------
__global__ void kD_detect(const int* __restrict__ eidx_w, const int* __restrict__ ety_w,
                          int* __restrict__ flags){
    int i = blockIdx.x*blockDim.x + threadIdx.x;
    int stride = gridDim.x*blockDim.x;
    int a0 = 0, a1 = 0;
    for (int w = 2*i+1; w < 2*N_EDGES; w += 2*stride) a0 |= eidx_w[w];
    for (int w = 2*i+1; w < N_EDGES;   w += 2*stride) a1 |= ety_w[w];
    if (a0) atomicOr(&flags[0], 1);
    if (a1) atomicOr(&flags[1], 1);
}

// ---------------- kN: normalize indices + dst histogram + per-edge rank ----------------
__global__ void kN_norm(const int* __restrict__ eidx_w, const int* __restrict__ ety_w,
                        const int* __restrict__ flags,
                        int* __restrict__ dst, int* __restrict__ srcty,
                        int* __restrict__ rankA, int* __restrict__ cnt){
    int i = blockIdx.x*blockDim.x + threadIdx.x;
    int stride = gridDim.x*blockDim.x;
    const bool e32 = (flags[0] != 0);
    const bool t32 = (flags[1] != 0);
    for (int e = i; e < N_EDGES; e += stride){
        int s, d, t;
        if (e32){ s = eidx_w[e];   d = eidx_w[N_EDGES + e]; }
        else    { s = eidx_w[2*e]; d = eidx_w[2*N_EDGES + 2*e]; }
        t = t32 ? ety_w[e] : ety_w[2*e];
        s = min(max(s, 0), N_NODES-1);
        d = min(max(d, 0), N_NODES-1);
        t = min(max(t, 0), 15);
        dst[e] = d; srcty[e] = s | (t << 20);
        rankA[e] = atomicAdd(&cnt[d], 1);   // within-node rank: free CSR slot
    }
}

// ---------------- kS: exclusive scan (4 elems/thread) -> row_ptr ----------------
__global__ __launch_bounds__(1024) void kS_scan(const int* __restrict__ cnt,
                                                int* __restrict__ row_ptr){
    __shared__ int sW[16];
    __shared__ int sWS[16];
    __shared__ int sbase;
    const int t = threadIdx.x, lane = t & 63, wv = t >> 6;
    if (t==0) sbase = 0;
    __syncthreads();
    for (int base=0; base<N_NODES; base+=4096){
        const int idx0 = base + t*4;
        int v0 = (idx0  <N_NODES) ? cnt[idx0  ] : 0;
        int v1 = (idx0+1<N_NODES) ? cnt[idx0+1] : 0;
        int v2 = (idx0+2<N_NODES) ? cnt[idx0+2] : 0;
        int v3 = (idx0+3<N_NODES) ? cnt[idx0+3] : 0;
        int p1 = v0+v1, p2 = p1+v2, tot = p2+v3;
        int xs = tot;
        #pragma unroll
        for (int off=1; off<64; off<<=1){
            int y = __shfl_up(xs, off, 64);
            if (lane >= off) xs += y;
        }
        if (lane==63) sW[wv] = xs;
        __syncthreads();
        if (t < 16){
            int wvv = sW[t], ws = wvv;
            #pragma unroll
            for (int off=1; off<16; off<<=1){
                int y = __shfl_up(ws, off, 16);
                if ((t&15) >= off) ws += y;
            }
            sWS[t] = ws - wvv;
        }
        __syncthreads();
        int ex = sbase + sWS[wv] + xs - tot;
        if (idx0  <N_NODES){ row_ptr[idx0  ]=ex;    }
        if (idx0+1<N_NODES){ row_ptr[idx0+1]=ex+v0; }
        if (idx0+2<N_NODES){ row_ptr[idx0+2]=ex+p1; }
        if (idx0+3<N_NODES){ row_ptr[idx0+3]=ex+p2; }
        __syncthreads();
        if (t==0) sbase += sWS[15] + sW[15];
        __syncthreads();
    }
    if (t==0) row_ptr[N_NODES] = sbase;
}

// ---------------- kPre: fused Mt/ATw (block 16) + Tw (blocks 0..15) ----------------
__global__ __launch_bounds__(256) void kPre(const float* __restrict__ gat_edge_W,
                                            const float* __restrict__ a_edge,
                                            const float* __restrict__ gat_emb,
                                            const float* __restrict__ gine_emb,
                                            const float* __restrict__ gine_edge_W,
                                            const float* __restrict__ gine_edge_b,
                                            float* __restrict__ Mt, float* __restrict__ ATw,
                                            float* __restrict__ Tw){
    const int t = threadIdx.x;
    if (blockIdx.x < 16){
        if (t < 128){
            const int tyv = blockIdx.x;
            float acc = gine_edge_b[t];
            #pragma unroll
            for (int d=0;d<32;d++) acc += gine_emb[tyv*32+d]*gine_edge_W[d*128+t];
            Tw[tyv*128+t] = acc;
        }
        return;
    }
    __shared__ float sM[32*8];
    const int d = t>>3, hh = t&7;
    float acc = 0.f;
    #pragma unroll
    for (int c=0;c<16;c++) acc += gat_edge_W[d*128 + hh*16 + c]*a_edge[hh*16 + c];
    sM[d*8+hh] = acc; Mt[hh*32 + d] = acc;
    __syncthreads();
    if (t < 128){
        int tyv = t>>3, h2 = t&7;
        float a = 0.f;
        #pragma unroll
        for (int dd=0;dd<32;dd++) a += gat_emb[tyv*32+dd]*sM[dd*8+h2];
        ATw[tyv*8+h2] = a;
    }
}

// ---------------- kW: pack W1/W2/comb_W/gat_W into MFMA fragment-ordered f16 ----------------
// chunk: (kstep, nblk): lane l (n=l&15,g=l>>4) holds W[kstep*32+8g+j][nblk*16+n], j=0..7.
__global__ __launch_bounds__(256) void kW_pack(
    const float* __restrict__ W1, const float* __restrict__ W2,
    const float* __restrict__ combW, const float* __restrict__ gatW,
    unsigned* __restrict__ W1p, unsigned* __restrict__ W2p,
    unsigned* __restrict__ combp, unsigned* __restrict__ Wgp)
{
    const int tid = blockIdx.x*256 + threadIdx.x;
    const int chunk = tid >> 6;
    const int l = tid & 63;
    const int n = l & 15, g = l >> 4;
    const float* W; unsigned* P; int NCH, cbase;
    if (chunk < 32)      { W = W1;    P = W1p;   NCH = 128; cbase = chunk; }
    else if (chunk < 64) { W = W2;    P = W2p;   NCH = 128; cbase = chunk - 32; }
    else if (chunk < 192){ W = combW; P = combp; NCH = 256; cbase = chunk - 64; }
    else if (chunk < 224){ W = gatW;  P = Wgp;   NCH = 128; cbase = chunk - 192; }
    else return;
    const int nblocks = NCH/16;
    const int kstep = cbase / nblocks, nblk = cbase % nblocks;
    const int k0 = kstep*32 + 8*g, col = nblk*16 + n;
    unsigned u0 = packh2(W[(size_t)(k0+0)*NCH + col], W[(size_t)(k0+1)*NCH + col]);
    unsigned u1 = packh2(W[(size_t)(k0+2)*NCH + col], W[(size_t)(k0+3)*NCH + col]);
    unsigned u2 = packh2(W[(size_t)(k0+4)*NCH + col], W[(size_t)(k0+5)*NCH + col]);
    unsigned u3 = packh2(W[(size_t)(k0+6)*NCH + col], W[(size_t)(k0+7)*NCH + col]);
    ((uint4*)P)[(size_t)cbase*64 + l] = make_uint4(u0,u1,u2,u3);
}

// ---------------- k1: MFMA node prep — h = x@gat_W, pack xhb, a_s/a_d ----------------
// 32 nodes/block, 4 waves; x split hi/lo f16 (2 MFMAs per frag) for fp32-grade h.
#define K1N 32
__global__ __launch_bounds__(256) void k1_node_prep(
    const float* __restrict__ x, const unsigned* __restrict__ Wgp,
    const float* __restrict__ a_src, const float* __restrict__ a_dst,
    unsigned* __restrict__ xhb, float* __restrict__ as_out, float* __restrict__ ad_out)
{
    __shared__ _Float16 sXhi[K1N][136];
    __shared__ _Float16 sXlo[K1N][136];
    __shared__ float sH[K1N][132];
    const int t = threadIdx.x;
    const int l = t & 63, wid = t >> 6;
    const int n = l & 15, g = l >> 4;
    const int base = blockIdx.x*K1N;

    // stage x (hi/lo f16) + write x-part of xhb
    for (int i = t; i < K1N*32; i += 256){
        const int node = i >> 5, c4 = i & 31;
        float4 xv = ((const float4*)x)[(size_t)(base+node)*32 + c4];
        _Float16 f0=(_Float16)xv.x, f1=(_Float16)xv.y, f2=(_Float16)xv.z, f3=(_Float16)xv.w;
        h2v p01; p01.x=f0; p01.y=f1;  h2v p23; p23.x=f2; p23.y=f3;
        unsigned u01 = __builtin_bit_cast(unsigned,p01);
        unsigned u23 = __builtin_bit_cast(unsigned,p23);
        *(uint2*)&sXhi[node][c4*4] = make_uint2(u01,u23);
        h2v q01,q23;
        q01.x=(_Float16)(xv.x-(float)f0); q01.y=(_Float16)(xv.y-(float)f1);
        q23.x=(_Float16)(xv.z-(float)f2); q23.y=(_Float16)(xv.w-(float)f3);
        *(uint2*)&sXlo[node][c4*4] = make_uint2(__builtin_bit_cast(unsigned,q01),
                                                __builtin_bit_cast(unsigned,q23));
        ((uint2*)xhb)[(size_t)(base+node)*64 + c4] = make_uint2(u01,u23);
    }
    __syncthreads();

    // h = x @ gat_W  (wave's 32-ch slice)
    f32x4v acc[2][2];
    #pragma unroll
    for (int mt=0;mt<2;mt++)
        #pragma unroll
        for (int nt=0;nt<2;nt++) acc[mt][nt] = (f32x4v){0.f,0.f,0.f,0.f};
    #pragma unroll
    for (int ks=0;ks<4;ks++){
        h16x8 bfr[2];
        #pragma unroll
        for (int nt=0;nt<2;nt++){
            uint4 u = ((const uint4*)Wgp)[(size_t)((ks*8 + 2*wid + nt)*64 + l)];
            bfr[nt] = __builtin_bit_cast(h16x8, u);
        }
        #pragma unroll
        for (int mt=0;mt<2;mt++){
            const int row = 16*mt + n;
            h16x8 ahi = *(const h16x8*)&sXhi[row][8*g + 32*ks];
            h16x8 alo = *(const h16x8*)&sXlo[row][8*g + 32*ks];
            #pragma unroll
            for (int nt=0;nt<2;nt++){
                acc[mt][nt] = __builtin_amdgcn_mfma_f32_16x16x32_f16(ahi, bfr[nt], acc[mt][nt], 0,0,0);
                acc[mt][nt] = __builtin_amdgcn_mfma_f32_16x16x32_f16(alo, bfr[nt], acc[mt][nt], 0,0,0);
            }
        }
    }
    // D: col=n (channel 32wid+16nt+n), row=16mt+4g+r
    #pragma unroll
    for (int mt=0;mt<2;mt++)
        #pragma unroll
        for (int nt=0;nt<2;nt++)
            #pragma unroll
            for (int r=0;r<4;r++)
                sH[16*mt + 4*g + r][32*wid + 16*nt + n] = acc[mt][nt][r];
    __syncthreads();

    // pack h-part of xhb
    for (int i = t; i < K1N*64; i += 256){
        const int node = i >> 6, w = i & 63;
        xhb[(size_t)(base+node)*128 + 64 + w] = packh2(sH[node][2*w], sH[node][2*w+1]);
    }
    // a_s/a_d: one (node, head) per thread
    {
        const int node = t >> 3, head = t & 7;
        float vs = 0.f, vd = 0.f;
        #pragma unroll
        for (int j=0;j<16;j++){
            float hv = sH[node][head*16 + j];
            vs += hv*a_src[head*16 + j];
            vd += hv*a_dst[head*16 + j];
        }
        as_out[(size_t)(base+node)*8 + head] = vs;
        ad_out[(size_t)(base+node)*8 + head] = vd;
    }
}

// ---------------- kCE: barrier-free, atomic-free edge precompute ----------------
// 8 lanes per edge (q=head). pos = row_ptr[d] + rank (precomputed in kN).
// Writes one full 128B record per edge: [evb f16x32 | p f32x8 | sty x8].
__global__ __launch_bounds__(256) void kCE_edge(
    const float* __restrict__ eattr,
    const int* __restrict__ dstA, const int* __restrict__ styA,
    const int* __restrict__ rankA, const int* __restrict__ rowp,
    const float* __restrict__ a_s, const float* __restrict__ a_d,
    const float* __restrict__ Mt, const float* __restrict__ ATw,
    const float* __restrict__ gine_emb,
    unsigned* __restrict__ erec)
{
    const int t = threadIdx.x;
    const int q = t & 7;
    // preload this lane's 4-dim slice of all 8 head vectors (Mt is [8][32])
    float4 mtr[8];
    #pragma unroll
    for (int h=0;h<8;h++) mtr[h] = ((const float4*)Mt)[h*8 + q];

    const int e0 = (blockIdx.x*256 + t) >> 3;
    const int estride = (gridDim.x*256) >> 3;
    for (int e = e0; e < N_EDGES; e += estride){
        float4 f = ((const float4*)eattr)[(size_t)e*8 + q];
        const int d    = dstA[e];
        const int sty  = styA[e];
        const int pos  = rowp[d] + rankA[e];
        const int srcn = sty & 0xFFFFF;
        const int tyv  = ((unsigned)sty)>>20;

        // attrs: f16(eattr + gine_type_emb)
        const float4 ge = ((const float4*)gine_emb)[tyv*8 + q];
        ((uint2*)erec)[(size_t)pos*16 + q] =
            make_uint2(packh2(f.x+ge.x, f.y+ge.y), packh2(f.z+ge.z, f.w+ge.w));

        // per-lane partial dot for every head (32 FMA)
        float ph[8];
        #pragma unroll
        for (int h=0;h<8;h++)
            ph[h] = f.x*mtr[h].x + f.y*mtr[h].y + f.z*mtr[h].z + f.w*mtr[h].w;
        // 3-step reduce-scatter within the 8-lane group -> lane q holds head q's dot
        #pragma unroll
        for (int i=0;i<4;i++){
            float send = (q&1) ? ph[2*i] : ph[2*i+1];
            float recv = __shfl_xor(send, 1, 64);
            ph[i] = ((q&1) ? ph[2*i+1] : ph[2*i]) + recv;
        }
        #pragma unroll
        for (int i=0;i<2;i++){
            float send = (q&2) ? ph[2*i] : ph[2*i+1];
            float recv = __shfl_xor(send, 2, 64);
            ph[i] = ((q&2) ? ph[2*i+1] : ph[2*i]) + recv;
        }
        {
            float send = (q&4) ? ph[0] : ph[1];
            float recv = __shfl_xor(send, 4, 64);
            ph[0] = ((q&4) ? ph[1] : ph[0]) + recv;
        }

        float lg = a_s[srcn*8+q] + a_d[d*8+q] + ph[0] + ATw[tyv*8+q];
        lg = (lg>0.f) ? lg : 0.2f*lg;
        ((float*)erec)[(size_t)pos*32 + 16 + q] = __expf(lg);
        ((int*)erec)[(size_t)pos*32 + 24 + q] = sty;   // fills rest of the 128B line
    }
}

// ---------------- k3: MFMA-based CSR gather (reads 128B records) ----------------
template<bool MASK>
__device__ __forceinline__ void gine_block16(
    int pos0, int rem, int m, int g,
    const unsigned* __restrict__ xhb, const unsigned* __restrict__ erec,
    const h16x8* aw, const float* bb,
    float* accA, float* accG, float* ps)
{
    const int mc = MASK ? (m < rem ? m : rem - 1) : m;
    u32x4v uu = ((const u32x4v*)erec)[(size_t)(pos0 + mc)*8 + g];
    h16x8 evf = __builtin_bit_cast(h16x8, uu);

    const _Float16* xp[4];
    int ecl[4];
    #pragma unroll
    for (int r=0;r<4;r++){
        const int er = 4*g + r;
        const int ec = MASK ? (er < rem ? er : rem - 1) : er;
        ecl[r] = pos0 + ec;
        const int srcn = ((const int*)erec)[(size_t)(pos0 + ec)*32 + 24] & 0xFFFFF;
        xp[r] = (const _Float16*)(xhb + (size_t)srcn*128) + m;
    }
    #pragma unroll
    for (int hf4=0; hf4<2; hf4++){
        f32x4v pv[4];
        #pragma unroll
        for (int r=0;r<4;r++){
            pv[r] = *(const f32x4v*)((const float*)erec + (size_t)ecl[r]*32 + 16 + hf4*4);
            if (MASK && (4*g + r) >= rem) pv[r] = (f32x4v){0.f,0.f,0.f,0.f};
        }
        #pragma unroll
        for (int r=0;r<4;r++){
            ps[hf4*4+0] += pv[r][0]; ps[hf4*4+1] += pv[r][1];
            ps[hf4*4+2] += pv[r][2]; ps[hf4*4+3] += pv[r][3];
        }
        #pragma unroll
        for (int cc=0; cc<4; cc++){
            const int c = hf4*4 + cc;
            f32x4v Dv = { bb[c], bb[c], bb[c], bb[c] };
            Dv = __builtin_amdgcn_mfma_f32_16x16x32_f16(evf, aw[c], Dv, 0, 0, 0);
            #pragma unroll
            for (int r=0;r<4;r++){
                float xf = (float)xp[r][c*16];
                float hf = (float)xp[r][128 + c*16];
                float tmp = fmaxf(xf + Dv[r], 0.f);
                if (MASK && (4*g + r) >= rem) tmp = 0.f;
                accA[c] += tmp;
                accG[c] += pv[r][cc] * hf;
            }
        }
    }
}

__global__ __launch_bounds__(256) void k3_gather(
    const unsigned* __restrict__ xhb, const unsigned* __restrict__ erec,
    const int* __restrict__ row_ptr,
    const float* __restrict__ gine_b, const float* __restrict__ gine_W,
    float* __restrict__ agg, float* __restrict__ gacc)
{
    const int t = threadIdx.x;
    const int lane = t & 63;
    const int m = lane & 15;
    const int g = lane >> 4;

    h16x8 aw[8];
    #pragma unroll
    for (int c=0;c<8;c++){
        #pragma unroll
        for (int j=0;j<8;j++)
            aw[c][j] = (_Float16)gine_W[(8*g + j)*128 + c*16 + m];
    }
    float bb[8];
    #pragma unroll
    for (int c=0;c<8;c++) bb[c] = gine_b[c*16 + m];

    const int nwaves = gridDim.x*4;
    for (int d = blockIdx.x*4 + (t>>6); d < N_NODES; d += nwaves){
        const int row = row_ptr[d], end = row_ptr[d+1];
        float accA[8] = {0,0,0,0,0,0,0,0};
        float accG[8] = {0,0,0,0,0,0,0,0};
        float ps[8]   = {0,0,0,0,0,0,0,0};
        const int deg = end - row;
        int pos0 = row;
        const int nfull = deg >> 4;
        for (int b=0;b<nfull;b++, pos0+=16)
            gine_block16<false>(pos0, 16, m, g, xhb, erec, aw, bb, accA, accG, ps);
        const int rem = deg & 15;
        if (rem)
            gine_block16<true>(pos0, rem, m, g, xhb, erec, aw, bb, accA, accG, ps);
        #pragma unroll
        for (int c=0;c<8;c++){
            accA[c] += __shfl_xor(accA[c], 16, 64);
            accA[c] += __shfl_xor(accA[c], 32, 64);
            accG[c] += __shfl_xor(accG[c], 16, 64);
            accG[c] += __shfl_xor(accG[c], 32, 64);
            ps[c]   += __shfl_xor(ps[c],   16, 64);
            ps[c]   += __shfl_xor(ps[c],   32, 64);
        }
        if (g == 0){
            #pragma unroll
            for (int c=0;c<8;c++){
                const float inv = 1.f/(ps[c] + 1e-16f);
                agg [(size_t)d*128 + c*16 + m] = accA[c];
                gacc[(size_t)d*128 + c*16 + m] = accG[c]*inv;
            }
        }
    }
}

// ---------------- k4: MFMA final node kernel ----------------
#define K4N 32
__global__ __launch_bounds__(256) void k4_final(
    const float* __restrict__ x, const float* __restrict__ agg, const float* __restrict__ gacc,
    const float* __restrict__ gat_b, const float* __restrict__ eps_p,
    const unsigned* __restrict__ W1p, const float* __restrict__ b1,
    const unsigned* __restrict__ W2p, const float* __restrict__ gb2,
    const unsigned* __restrict__ combp, const float* __restrict__ comb_b,
    const float* __restrict__ ln_g, const float* __restrict__ ln_b,
    float* __restrict__ out)
{
    __shared__ _Float16 sHi[K4N][136];
    __shared__ _Float16 sLo[K4N][136];
    __shared__ _Float16 sCH[K4N][264];
    __shared__ float sRed[K4N][8];
    __shared__ float sMV[K4N][2];
    const int t = threadIdx.x;
    const int l = t & 63, wid = t >> 6;
    const int n = l & 15, g = l >> 4;
    const float epsv = 1.f + eps_p[0];
    const int base = blockIdx.x*K4N;

    for (int i = t; i < K4N*32; i += 256){
        const int node = i >> 5, c4 = i & 31;
        float4 xv = ((const float4*)x   )[(size_t)(base+node)*32 + c4];
        float4 av = ((const float4*)agg )[(size_t)(base+node)*32 + c4];
        float4 gv = ((const float4*)gacc)[(size_t)(base+node)*32 + c4];
        float4 bv = ((const float4*)gat_b)[c4];
        float h0 = epsv*xv.x + av.x, h1 = epsv*xv.y + av.y;
        float h2_ = epsv*xv.z + av.z, h3 = epsv*xv.w + av.w;
        _Float16 f0=(_Float16)h0, f1=(_Float16)h1, f2=(_Float16)h2_, f3=(_Float16)h3;
        h2v p01; p01.x=f0; p01.y=f1;  h2v p23; p23.x=f2; p23.y=f3;
        *(uint2*)&sHi[node][c4*4] = make_uint2(__builtin_bit_cast(unsigned,p01),
                                               __builtin_bit_cast(unsigned,p23));
        h2v q01, q23;
        q01.x=(_Float16)(h0-(float)f0); q01.y=(_Float16)(h1-(float)f1);
        q23.x=(_Float16)(h2_-(float)f2); q23.y=(_Float16)(h3-(float)f3);
        *(uint2*)&sLo[node][c4*4] = make_uint2(__builtin_bit_cast(unsigned,q01),
                                               __builtin_bit_cast(unsigned,q23));
        *(uint2*)&sCH[node][c4*4] = make_uint2(packh2(gv.x+bv.x, gv.y+bv.y),
                                               packh2(gv.z+bv.z, gv.w+bv.w));
    }
    __syncthreads();

    f32x4v acc1[2][2];
    #pragma unroll
    for (int mt=0;mt<2;mt++)
        #pragma unroll
        for (int nt=0;nt<2;nt++){
            float b = b1[32*wid + 16*nt + n];
            acc1[mt][nt] = (f32x4v){b,b,b,b};
        }
    #pragma unroll
    for (int ks=0;ks<4;ks++){
        h16x8 bfr[2];
        #pragma unroll
        for (int nt=0;nt<2;nt++){
            uint4 u = ((const uint4*)W1p)[(size_t)((ks*8 + 2*wid + nt)*64 + l)];
            bfr[nt] = __builtin_bit_cast(h16x8, u);
        }
        #pragma unroll
        for (int mt=0;mt<2;mt++){
            const int row = 16*mt + n;
            h16x8 ahi = *(const h16x8*)&sHi[row][8*g + 32*ks];
            h16x8 alo = *(const h16x8*)&sLo[row][8*g + 32*ks];
            #pragma unroll
            for (int nt=0;nt<2;nt++){
                acc1[mt][nt] = __builtin_amdgcn_mfma_f32_16x16x32_f16(ahi, bfr[nt], acc1[mt][nt], 0,0,0);
                acc1[mt][nt] = __builtin_amdgcn_mfma_f32_16x16x32_f16(alo, bfr[nt], acc1[mt][nt], 0,0,0);
            }
        }
    }
    __syncthreads();
    #pragma unroll
    for (int mt=0;mt<2;mt++)
        #pragma unroll
        for (int nt=0;nt<2;nt++)
            #pragma unroll
            for (int r=0;r<4;r++)
                sHi[16*mt + 4*g + r][32*wid + 16*nt + n] = (_Float16)fmaxf(acc1[mt][nt][r], 0.f);
    __syncthreads();

    f32x4v acc2[2][2];
    #pragma unroll
    for (int mt=0;mt<2;mt++)
        #pragma unroll
        for (int nt=0;nt<2;nt++){
            float b = gb2[32*wid + 16*nt + n];
            acc2[mt][nt] = (f32x4v){b,b,b,b};
        }
    #pragma unroll
    for (int ks=0;ks<4;ks++){
        h16x8 bfr[2];
        #pragma unroll
        for (int nt=0;nt<2;nt++){
            uint4 u = ((const uint4*)W2p)[(size_t)((ks*8 + 2*wid + nt)*64 + l)];
            bfr[nt] = __builtin_bit_cast(h16x8, u);
        }
        #pragma unroll
        for (int mt=0;mt<2;mt++){
            h16x8 a = *(const h16x8*)&sHi[16*mt + n][8*g + 32*ks];
            #pragma unroll
            for (int nt=0;nt<2;nt++)
                acc2[mt][nt] = __builtin_amdgcn_mfma_f32_16x16x32_f16(a, bfr[nt], acc2[mt][nt], 0,0,0);
        }
    }
    #pragma unroll
    for (int mt=0;mt<2;mt++)
        #pragma unroll
        for (int nt=0;nt<2;nt++)
            #pragma unroll
            for (int r=0;r<4;r++)
                sCH[16*mt + 4*g + r][128 + 32*wid + 16*nt + n] = (_Float16)acc2[mt][nt][r];
    __syncthreads();

    f32x4v accC[2][4];
    #pragma unroll
    for (int mt=0;mt<2;mt++)
        #pragma unroll
        for (int nt=0;nt<4;nt++){
            float b = comb_b[64*wid + 16*nt + n];
            accC[mt][nt] = (f32x4v){b,b,b,b};
        }
    #pragma unroll
    for (int ks=0;ks<8;ks++){
        h16x8 bfr[4];
        #pragma unroll
        for (int nt=0;nt<4;nt++){
            uint4 u = ((const uint4*)combp)[(size_t)((ks*16 + 4*wid + nt)*64 + l)];
            bfr[nt] = __builtin_bit_cast(h16x8, u);
        }
        #pragma unroll
        for (int mt=0;mt<2;mt++){
            h16x8 a = *(const h16x8*)&sCH[16*mt + n][8*g + 32*ks];
            #pragma unroll
            for (int nt=0;nt<4;nt++)
                accC[mt][nt] = __builtin_amdgcn_mfma_f32_16x16x32_f16(a, bfr[nt], accC[mt][nt], 0,0,0);
        }
    }

    #pragma unroll
    for (int mt=0;mt<2;mt++)
        #pragma unroll
        for (int r=0;r<4;r++){
            float s1=0.f, s2=0.f;
            #pragma unroll
            for (int nt=0;nt<4;nt++){ float z = accC[mt][nt][r]; s1 += z; s2 += z*z; }
            #pragma unroll
            for (int off=1; off<16; off<<=1){ s1 += __shfl_xor(s1,off,16); s2 += __shfl_xor(s2,off,16); }
            if (n==0){
                sRed[16*mt + 4*g + r][2*wid  ] = s1;
                sRed[16*mt + 4*g + r][2*wid+1] = s2;
            }
        }
    __syncthreads();
    if (t < K4N){
        float a1 = sRed[t][0]+sRed[t][2]+sRed[t][4]+sRed[t][6];
        float a2 = sRed[t][1]+sRed[t][3]+sRed[t][5]+sRed[t][7];
        float mu = a1*(1.f/256.f);
        float var = a2*(1.f/256.f) - mu*mu;
        sMV[t][0] = mu; sMV[t][1] = rsqrtf(var + 1e-5f);
    }
    __syncthreads();
    float lg[4], lb[4];
    #pragma unroll
    for (int nt=0;nt<4;nt++){ int ch = 64*wid + 16*nt + n; lg[nt]=ln_g[ch]; lb[nt]=ln_b[ch]; }
    #pragma unroll
    for (int mt=0;mt<2;mt++)
        #pragma unroll
        for (int r=0;r<4;r++){
            const int row = 16*mt + 4*g + r;
            const float mu = sMV[row][0], rs = sMV[row][1];
            #pragma unroll
            for (int nt=0;nt<4;nt++){
                const int ch = 64*wid + 16*nt + n;
                float zz = accC[mt][nt][r];
                out[(size_t)(base+row)*256 + ch] = fmaxf((zz-mu)*rs*lg[nt] + lb[nt], 0.f);
            }
        }
}

extern "C" void kernel_launch(void* const* d_in, const int* in_sizes, int n_in,
                              void* d_out, int out_size, void* d_ws, size_t ws_size,
                              hipStream_t stream)
{
    (void)in_sizes; (void)n_in; (void)out_size; (void)ws_size;
    const float* x           = (const float*)d_in[0];
    const int*   eidx_w      = (const int*)  d_in[1];
    const float* eattr       = (const float*)d_in[2];
    const int*   ety_w       = (const int*)  d_in[3];
    const float* gat_W       = (const float*)d_in[4];
    const float* gat_b       = (const float*)d_in[5];
    const float* gat_edge_W  = (const float*)d_in[6];
    const float* a_src       = (const float*)d_in[7];
    const float* a_dst       = (const float*)d_in[8];
    const float* a_edge      = (const float*)d_in[9];
    const float* gat_emb     = (const float*)d_in[10];
    const float* gine_emb    = (const float*)d_in[11];
    const float* gine_edge_W = (const float*)d_in[12];
    const float* gine_edge_b = (const float*)d_in[13];
    const float* gine_eps    = (const float*)d_in[14];
    const float* W1          = (const float*)d_in[15];
    const float* b1          = (const float*)d_in[16];
    const float* W2          = (const float*)d_in[17];
    const float* gb2         = (const float*)d_in[18];
    const float* comb_W      = (const float*)d_in[19];
    const float* comb_b      = (const float*)d_in[20];
    const float* ln_g        = (const float*)d_in[21];
    const float* ln_b        = (const float*)d_in[22];
    float* out = (float*)d_out;

    char* ws = (char*)d_ws;
    size_t off = 0;
    auto alloc = [&](size_t bytes)->void*{ void* p = ws + off; off += (bytes + 255)/256*256; return p; };
    size_t zero_start = off;
    int*      flags  = (int*)     alloc(256);
    int*      cnt    = (int*)     alloc((size_t)N_NODES*4);
    size_t zero_bytes = off - zero_start;
    int*      dstA   = (int*)     alloc((size_t)N_EDGES*4);
    int*      styA   = (int*)     alloc((size_t)N_EDGES*4);
    int*      rankA  = (int*)     alloc((size_t)N_EDGES*4);
    int*      rowp   = (int*)     alloc((size_t)(N_NODES+1)*4);
    unsigned* erec   = (unsigned*)alloc((size_t)N_EDGES*128);
    unsigned* xhb    = (unsigned*)alloc((size_t)N_NODES*128*4);
    float*    a_s    = (float*)   alloc((size_t)N_NODES*8*4);
    float*    a_d    = (float*)   alloc((size_t)N_NODES*8*4);
    float*    Mt     = (float*)   alloc(32*8*4);
    float*    ATw    = (float*)   alloc(16*8*4);
    float*    Tw     = (float*)   alloc(16*128*4);
    float*    agg    = (float*)   alloc((size_t)N_NODES*128*4);
    float*    gacc   = (float*)   alloc((size_t)N_NODES*128*4);
    unsigned* W1p    = (unsigned*)alloc((size_t)32*1024);
    unsigned* W2p    = (unsigned*)alloc((size_t)32*1024);
    unsigned* combp  = (unsigned*)alloc((size_t)128*1024);
    unsigned* Wgp    = (unsigned*)alloc((size_t)32*1024);

    int n4 = (int)(zero_bytes/16);
    k0_zero<<<(n4+255)/256, 256, 0, stream>>>((float4*)(ws + zero_start), n4);
    kD_detect<<<512, 256, 0, stream>>>(eidx_w, ety_w, flags);
    kN_norm<<<1024, 256, 0, stream>>>(eidx_w, ety_w, flags, dstA, styA, rankA, cnt);
    kS_scan<<<1, 1024, 0, stream>>>(cnt, rowp);

    kW_pack<<<56, 256, 0, stream>>>(W1, W2, comb_W, gat_W, W1p, W2p, combp, Wgp);
    kPre<<<17, 256, 0, stream>>>(gat_edge_W, a_edge, gat_emb, gine_emb,
                                 gine_edge_W, gine_edge_b, Mt, ATw, Tw);
    k1_node_prep<<<N_NODES/K1N, 256, 0, stream>>>(x, Wgp, a_src, a_dst, xhb, a_s, a_d);

    kCE_edge<<<2500, 256, 0, stream>>>(eattr, dstA, styA, rankA, rowp,
                                       a_s, a_d, Mt, ATw, gine_emb, erec);

    k3_gather<<<2500, 256, 0, stream>>>(xhb, erec, rowp,
                                        gine_edge_b, gine_edge_W, agg, gacc);

    k4_final<<<N_NODES/K4N, 256, 0, stream>>>(x, agg, gacc, gat_b, gine_eps,
                                              W1p, b1, W2p, gb2, combp, comb_b,
                                              ln_g, ln_b, out);
}

// Round 6
// 403.379 us; speedup vs baseline: 1.2407x; 1.0060x over previous
//
#include <hip/hip_runtime.h>

#define N_NODES 20000
#define N_EDGES 640000

typedef _Float16 h2v   __attribute__((ext_vector_type(2)));
typedef _Float16 h16x8 __attribute__((ext_vector_type(8)));
typedef float    f32x4v __attribute__((ext_vector_type(4)));
typedef unsigned u32x4v __attribute__((ext_vector_type(4)));

__device__ __forceinline__ unsigned packh2(float a, float b){
    h2v v; v.x = (_Float16)a; v.y = (_Float16)b;
    return __builtin_bit_cast(unsigned, v);
}

// ---------------- k0: zero flags + histogram counters ----------------
__global__ void k0_zero(float4* __restrict__ p, int n4){
    int i = blockIdx.x*blockDim.x + threadIdx.x;
    int stride = gridDim.x*blockDim.x;
    float4 z; z.x=0.f; z.y=0.f; z.z=0.f; z.w=0.f;
    for (; i<n4; i+=stride) p[i] = z;
}

// ---------------- kD: detect int32 vs int64 index buffers ----------------
__global__ void kD_detect(const int* __restrict__ eidx_w, const int* __restrict__ ety_w,
                          int* __restrict__ flags){
    int i = blockIdx.x*blockDim.x + threadIdx.x;
    int stride = gridDim.x*blockDim.x;
    int a0 = 0, a1 = 0;
    for (int w = 2*i+1; w < 2*N_EDGES; w += 2*stride) a0 |= eidx_w[w];
    for (int w = 2*i+1; w < N_EDGES;   w += 2*stride) a1 |= ety_w[w];
    if (a0) atomicOr(&flags[0], 1);
    if (a1) atomicOr(&flags[1], 1);
}

// ---------------- kN: normalize indices + dst histogram + per-edge rank ----------------
__global__ void kN_norm(const int* __restrict__ eidx_w, const int* __restrict__ ety_w,
                        const int* __restrict__ flags,
                        int* __restrict__ dst, int* __restrict__ srcty,
                        int* __restrict__ rankA, int* __restrict__ cnt){
    int i = blockIdx.x*blockDim.x + threadIdx.x;
    int stride = gridDim.x*blockDim.x;
    const bool e32 = (flags[0] != 0);
    const bool t32 = (flags[1] != 0);
    for (int e = i; e < N_EDGES; e += stride){
        int s, d, t;
        if (e32){ s = eidx_w[e];   d = eidx_w[N_EDGES + e]; }
        else    { s = eidx_w[2*e]; d = eidx_w[2*N_EDGES + 2*e]; }
        t = t32 ? ety_w[e] : ety_w[2*e];
        s = min(max(s, 0), N_NODES-1);
        d = min(max(d, 0), N_NODES-1);
        t = min(max(t, 0), 15);
        dst[e] = d; srcty[e] = s | (t << 20);
        rankA[e] = atomicAdd(&cnt[d], 1);   // within-node rank: free CSR slot
    }
}

// ---------------- kS: exclusive scan (4 elems/thread) -> row_ptr ----------------
__global__ __launch_bounds__(1024) void kS_scan(const int* __restrict__ cnt,
                                                int* __restrict__ row_ptr){
    __shared__ int sW[16];
    __shared__ int sWS[16];
    __shared__ int sbase;
    const int t = threadIdx.x, lane = t & 63, wv = t >> 6;
    if (t==0) sbase = 0;
    __syncthreads();
    for (int base=0; base<N_NODES; base+=4096){
        const int idx0 = base + t*4;
        int v0 = (idx0  <N_NODES) ? cnt[idx0  ] : 0;
        int v1 = (idx0+1<N_NODES) ? cnt[idx0+1] : 0;
        int v2 = (idx0+2<N_NODES) ? cnt[idx0+2] : 0;
        int v3 = (idx0+3<N_NODES) ? cnt[idx0+3] : 0;
        int p1 = v0+v1, p2 = p1+v2, tot = p2+v3;
        int xs = tot;
        #pragma unroll
        for (int off=1; off<64; off<<=1){
            int y = __shfl_up(xs, off, 64);
            if (lane >= off) xs += y;
        }
        if (lane==63) sW[wv] = xs;
        __syncthreads();
        if (t < 16){
            int wvv = sW[t], ws = wvv;
            #pragma unroll
            for (int off=1; off<16; off<<=1){
                int y = __shfl_up(ws, off, 16);
                if ((t&15) >= off) ws += y;
            }
            sWS[t] = ws - wvv;
        }
        __syncthreads();
        int ex = sbase + sWS[wv] + xs - tot;
        if (idx0  <N_NODES){ row_ptr[idx0  ]=ex;    }
        if (idx0+1<N_NODES){ row_ptr[idx0+1]=ex+v0; }
        if (idx0+2<N_NODES){ row_ptr[idx0+2]=ex+p1; }
        if (idx0+3<N_NODES){ row_ptr[idx0+3]=ex+p2; }
        __syncthreads();
        if (t==0) sbase += sWS[15] + sW[15];
        __syncthreads();
    }
    if (t==0) row_ptr[N_NODES] = sbase;
}

// ---------------- kPre: fused Mt/ATw (block 16) + Tw (blocks 0..15) ----------------
__global__ __launch_bounds__(256) void kPre(const float* __restrict__ gat_edge_W,
                                            const float* __restrict__ a_edge,
                                            const float* __restrict__ gat_emb,
                                            const float* __restrict__ gine_emb,
                                            const float* __restrict__ gine_edge_W,
                                            const float* __restrict__ gine_edge_b,
                                            float* __restrict__ Mt, float* __restrict__ ATw,
                                            float* __restrict__ Tw){
    const int t = threadIdx.x;
    if (blockIdx.x < 16){
        if (t < 128){
            const int tyv = blockIdx.x;
            float acc = gine_edge_b[t];
            #pragma unroll
            for (int d=0;d<32;d++) acc += gine_emb[tyv*32+d]*gine_edge_W[d*128+t];
            Tw[tyv*128+t] = acc;
        }
        return;
    }
    __shared__ float sM[32*8];
    const int d = t>>3, hh = t&7;
    float acc = 0.f;
    #pragma unroll
    for (int c=0;c<16;c++) acc += gat_edge_W[d*128 + hh*16 + c]*a_edge[hh*16 + c];
    sM[d*8+hh] = acc; Mt[hh*32 + d] = acc;
    __syncthreads();
    if (t < 128){
        int tyv = t>>3, h2 = t&7;
        float a = 0.f;
        #pragma unroll
        for (int dd=0;dd<32;dd++) a += gat_emb[tyv*32+dd]*sM[dd*8+h2];
        ATw[tyv*8+h2] = a;
    }
}

// ---------------- kW: pack W1/W2/comb_W/gat_W into MFMA fragment-ordered f16 ----------------
// chunk: (kstep, nblk): lane l (n=l&15,g=l>>4) holds W[kstep*32+8g+j][nblk*16+n], j=0..7.
__global__ __launch_bounds__(256) void kW_pack(
    const float* __restrict__ W1, const float* __restrict__ W2,
    const float* __restrict__ combW, const float* __restrict__ gatW,
    unsigned* __restrict__ W1p, unsigned* __restrict__ W2p,
    unsigned* __restrict__ combp, unsigned* __restrict__ Wgp)
{
    const int tid = blockIdx.x*256 + threadIdx.x;
    const int chunk = tid >> 6;
    const int l = tid & 63;
    const int n = l & 15, g = l >> 4;
    const float* W; unsigned* P; int NCH, cbase;
    if (chunk < 32)      { W = W1;    P = W1p;   NCH = 128; cbase = chunk; }
    else if (chunk < 64) { W = W2;    P = W2p;   NCH = 128; cbase = chunk - 32; }
    else if (chunk < 192){ W = combW; P = combp; NCH = 256; cbase = chunk - 64; }
    else if (chunk < 224){ W = gatW;  P = Wgp;   NCH = 128; cbase = chunk - 192; }
    else return;
    const int nblocks = NCH/16;
    const int kstep = cbase / nblocks, nblk = cbase % nblocks;
    const int k0 = kstep*32 + 8*g, col = nblk*16 + n;
    unsigned u0 = packh2(W[(size_t)(k0+0)*NCH + col], W[(size_t)(k0+1)*NCH + col]);
    unsigned u1 = packh2(W[(size_t)(k0+2)*NCH + col], W[(size_t)(k0+3)*NCH + col]);
    unsigned u2 = packh2(W[(size_t)(k0+4)*NCH + col], W[(size_t)(k0+5)*NCH + col]);
    unsigned u3 = packh2(W[(size_t)(k0+6)*NCH + col], W[(size_t)(k0+7)*NCH + col]);
    ((uint4*)P)[(size_t)cbase*64 + l] = make_uint4(u0,u1,u2,u3);
}

// ---------------- k1: MFMA node prep — h = x@gat_W, pack xhb interleaved, a_s/a_d ----------------
// 32 nodes/block, 4 waves; x split hi/lo f16 (2 MFMAs per frag) for fp32-grade h.
// xhb layout: dword ch of row n = (f16 x[n][ch], f16 h[n][ch])  -> k3 reads ONE dword per (edge,ch).
#define K1N 32
__global__ __launch_bounds__(256) void k1_node_prep(
    const float* __restrict__ x, const unsigned* __restrict__ Wgp,
    const float* __restrict__ a_src, const float* __restrict__ a_dst,
    unsigned* __restrict__ xhb, float* __restrict__ as_out, float* __restrict__ ad_out)
{
    __shared__ _Float16 sXhi[K1N][136];
    __shared__ _Float16 sXlo[K1N][136];
    __shared__ float sH[K1N][132];
    const int t = threadIdx.x;
    const int l = t & 63, wid = t >> 6;
    const int n = l & 15, g = l >> 4;
    const int base = blockIdx.x*K1N;

    // stage x (hi/lo f16)
    for (int i = t; i < K1N*32; i += 256){
        const int node = i >> 5, c4 = i & 31;
        float4 xv = ((const float4*)x)[(size_t)(base+node)*32 + c4];
        _Float16 f0=(_Float16)xv.x, f1=(_Float16)xv.y, f2=(_Float16)xv.z, f3=(_Float16)xv.w;
        h2v p01; p01.x=f0; p01.y=f1;  h2v p23; p23.x=f2; p23.y=f3;
        *(uint2*)&sXhi[node][c4*4] = make_uint2(__builtin_bit_cast(unsigned,p01),
                                                __builtin_bit_cast(unsigned,p23));
        h2v q01,q23;
        q01.x=(_Float16)(xv.x-(float)f0); q01.y=(_Float16)(xv.y-(float)f1);
        q23.x=(_Float16)(xv.z-(float)f2); q23.y=(_Float16)(xv.w-(float)f3);
        *(uint2*)&sXlo[node][c4*4] = make_uint2(__builtin_bit_cast(unsigned,q01),
                                                __builtin_bit_cast(unsigned,q23));
    }
    __syncthreads();

    // h = x @ gat_W  (wave's 32-ch slice)
    f32x4v acc[2][2];
    #pragma unroll
    for (int mt=0;mt<2;mt++)
        #pragma unroll
        for (int nt=0;nt<2;nt++) acc[mt][nt] = (f32x4v){0.f,0.f,0.f,0.f};
    #pragma unroll
    for (int ks=0;ks<4;ks++){
        h16x8 bfr[2];
        #pragma unroll
        for (int nt=0;nt<2;nt++){
            uint4 u = ((const uint4*)Wgp)[(size_t)((ks*8 + 2*wid + nt)*64 + l)];
            bfr[nt] = __builtin_bit_cast(h16x8, u);
        }
        #pragma unroll
        for (int mt=0;mt<2;mt++){
            const int row = 16*mt + n;
            h16x8 ahi = *(const h16x8*)&sXhi[row][8*g + 32*ks];
            h16x8 alo = *(const h16x8*)&sXlo[row][8*g + 32*ks];
            #pragma unroll
            for (int nt=0;nt<2;nt++){
                acc[mt][nt] = __builtin_amdgcn_mfma_f32_16x16x32_f16(ahi, bfr[nt], acc[mt][nt], 0,0,0);
                acc[mt][nt] = __builtin_amdgcn_mfma_f32_16x16x32_f16(alo, bfr[nt], acc[mt][nt], 0,0,0);
            }
        }
    }
    // D: col=n (channel 32wid+16nt+n), row=16mt+4g+r
    #pragma unroll
    for (int mt=0;mt<2;mt++)
        #pragma unroll
        for (int nt=0;nt<2;nt++)
            #pragma unroll
            for (int r=0;r<4;r++)
                sH[16*mt + 4*g + r][32*wid + 16*nt + n] = acc[mt][nt][r];
    __syncthreads();

    // pack xhb interleaved: dword ch = (x f16, h f16)
    for (int i = t; i < K1N*128; i += 256){
        const int node = i >> 7, ch = i & 127;
        xhb[(size_t)(base+node)*128 + ch] = packh2((float)sXhi[node][ch], sH[node][ch]);
    }
    // a_s/a_d: one (node, head) per thread
    {
        const int node = t >> 3, head = t & 7;
        float vs = 0.f, vd = 0.f;
        #pragma unroll
        for (int j=0;j<16;j++){
            float hv = sH[node][head*16 + j];
            vs += hv*a_src[head*16 + j];
            vd += hv*a_dst[head*16 + j];
        }
        as_out[(size_t)(base+node)*8 + head] = vs;
        ad_out[(size_t)(base+node)*8 + head] = vd;
    }
}

// ---------------- kCE: barrier-free, atomic-free edge precompute ----------------
// 8 lanes per edge (q=head). pos = row_ptr[d] + rank (precomputed in kN).
// Writes one full 128B record per edge: [evb f16x32 | p f32x8 | sty x8].
__global__ __launch_bounds__(256) void kCE_edge(
    const float* __restrict__ eattr,
    const int* __restrict__ dstA, const int* __restrict__ styA,
    const int* __restrict__ rankA, const int* __restrict__ rowp,
    const float* __restrict__ a_s, const float* __restrict__ a_d,
    const float* __restrict__ Mt, const float* __restrict__ ATw,
    const float* __restrict__ gine_emb,
    unsigned* __restrict__ erec)
{
    const int t = threadIdx.x;
    const int q = t & 7;
    // preload this lane's 4-dim slice of all 8 head vectors (Mt is [8][32])
    float4 mtr[8];
    #pragma unroll
    for (int h=0;h<8;h++) mtr[h] = ((const float4*)Mt)[h*8 + q];

    const int e0 = (blockIdx.x*256 + t) >> 3;
    const int estride = (gridDim.x*256) >> 3;
    for (int e = e0; e < N_EDGES; e += estride){
        float4 f = ((const float4*)eattr)[(size_t)e*8 + q];
        const int d    = dstA[e];
        const int sty  = styA[e];
        const int pos  = rowp[d] + rankA[e];
        const int srcn = sty & 0xFFFFF;
        const int tyv  = ((unsigned)sty)>>20;

        // attrs: f16(eattr + gine_type_emb)
        const float4 ge = ((const float4*)gine_emb)[tyv*8 + q];
        ((uint2*)erec)[(size_t)pos*16 + q] =
            make_uint2(packh2(f.x+ge.x, f.y+ge.y), packh2(f.z+ge.z, f.w+ge.w));

        // per-lane partial dot for every head (32 FMA)
        float ph[8];
        #pragma unroll
        for (int h=0;h<8;h++)
            ph[h] = f.x*mtr[h].x + f.y*mtr[h].y + f.z*mtr[h].z + f.w*mtr[h].w;
        // 3-step reduce-scatter within the 8-lane group -> lane q holds head q's dot
        #pragma unroll
        for (int i=0;i<4;i++){
            float send = (q&1) ? ph[2*i] : ph[2*i+1];
            float recv = __shfl_xor(send, 1, 64);
            ph[i] = ((q&1) ? ph[2*i+1] : ph[2*i]) + recv;
        }
        #pragma unroll
        for (int i=0;i<2;i++){
            float send = (q&2) ? ph[2*i] : ph[2*i+1];
            float recv = __shfl_xor(send, 2, 64);
            ph[i] = ((q&2) ? ph[2*i+1] : ph[2*i]) + recv;
        }
        {
            float send = (q&4) ? ph[0] : ph[1];
            float recv = __shfl_xor(send, 4, 64);
            ph[0] = ((q&4) ? ph[1] : ph[0]) + recv;
        }

        float lg = a_s[srcn*8+q] + a_d[d*8+q] + ph[0] + ATw[tyv*8+q];
        lg = (lg>0.f) ? lg : 0.2f*lg;
        ((float*)erec)[(size_t)pos*32 + 16 + q] = __expf(lg);
        ((int*)erec)[(size_t)pos*32 + 24 + q] = sty;   // fills rest of the 128B line
    }
}

// ---------------- k3: MFMA-based CSR gather (128B records, interleaved xhb) ----------------
template<bool MASK>
__device__ __forceinline__ void gine_block16(
    int pos0, int rem, int m, int g,
    const unsigned* __restrict__ xhb, const unsigned* __restrict__ erec,
    const h16x8* aw, const float* bb,
    float* accA, float* accG, float* ps)
{
    const int mc = MASK ? (m < rem ? m : rem - 1) : m;
    u32x4v uu = ((const u32x4v*)erec)[(size_t)(pos0 + mc)*8 + g];
    h16x8 evf = __builtin_bit_cast(h16x8, uu);

    const unsigned* xq[4];
    int ecl[4];
    #pragma unroll
    for (int r=0;r<4;r++){
        const int er = 4*g + r;
        const int ec = MASK ? (er < rem ? er : rem - 1) : er;
        ecl[r] = pos0 + ec;
        const int srcn = ((const int*)erec)[(size_t)(pos0 + ec)*32 + 24] & 0xFFFFF;
        xq[r] = xhb + (size_t)srcn*128 + m;   // dword (x,h) per channel; chunk c at +16c
    }
    #pragma unroll
    for (int hf4=0; hf4<2; hf4++){
        f32x4v pv[4];
        #pragma unroll
        for (int r=0;r<4;r++){
            pv[r] = *(const f32x4v*)((const float*)erec + (size_t)ecl[r]*32 + 16 + hf4*4);
            if (MASK && (4*g + r) >= rem) pv[r] = (f32x4v){0.f,0.f,0.f,0.f};
        }
        #pragma unroll
        for (int r=0;r<4;r++){
            ps[hf4*4+0] += pv[r][0]; ps[hf4*4+1] += pv[r][1];
            ps[hf4*4+2] += pv[r][2]; ps[hf4*4+3] += pv[r][3];
        }
        #pragma unroll
        for (int cc=0; cc<4; cc++){
            const int c = hf4*4 + cc;
            f32x4v Dv = { bb[c], bb[c], bb[c], bb[c] };
            Dv = __builtin_amdgcn_mfma_f32_16x16x32_f16(evf, aw[c], Dv, 0, 0, 0);
            #pragma unroll
            for (int r=0;r<4;r++){
                h2v xh = __builtin_bit_cast(h2v, xq[r][c*16]);
                float tmp = fmaxf((float)xh.x + Dv[r], 0.f);
                if (MASK && (4*g + r) >= rem) tmp = 0.f;
                accA[c] += tmp;
                accG[c] += pv[r][cc] * (float)xh.y;
            }
        }
    }
}

__global__ __launch_bounds__(256) void k3_gather(
    const unsigned* __restrict__ xhb, const unsigned* __restrict__ erec,
    const int* __restrict__ row_ptr,
    const float* __restrict__ gine_b, const float* __restrict__ gine_W,
    float* __restrict__ agg, float* __restrict__ gacc)
{
    const int t = threadIdx.x;
    const int lane = t & 63;
    const int m = lane & 15;
    const int g = lane >> 4;

    h16x8 aw[8];
    #pragma unroll
    for (int c=0;c<8;c++){
        #pragma unroll
        for (int j=0;j<8;j++)
            aw[c][j] = (_Float16)gine_W[(8*g + j)*128 + c*16 + m];
    }
    float bb[8];
    #pragma unroll
    for (int c=0;c<8;c++) bb[c] = gine_b[c*16 + m];

    const int nwaves = gridDim.x*4;
    for (int d = blockIdx.x*4 + (t>>6); d < N_NODES; d += nwaves){
        const int row = row_ptr[d], end = row_ptr[d+1];
        float accA[8] = {0,0,0,0,0,0,0,0};
        float accG[8] = {0,0,0,0,0,0,0,0};
        float ps[8]   = {0,0,0,0,0,0,0,0};
        const int deg = end - row;
        int pos0 = row;
        const int nfull = deg >> 4;
        for (int b=0;b<nfull;b++, pos0+=16)
            gine_block16<false>(pos0, 16, m, g, xhb, erec, aw, bb, accA, accG, ps);
        const int rem = deg & 15;
        if (rem)
            gine_block16<true>(pos0, rem, m, g, xhb, erec, aw, bb, accA, accG, ps);
        #pragma unroll
        for (int c=0;c<8;c++){
            accA[c] += __shfl_xor(accA[c], 16, 64);
            accA[c] += __shfl_xor(accA[c], 32, 64);
            accG[c] += __shfl_xor(accG[c], 16, 64);
            accG[c] += __shfl_xor(accG[c], 32, 64);
            ps[c]   += __shfl_xor(ps[c],   16, 64);
            ps[c]   += __shfl_xor(ps[c],   32, 64);
        }
        if (g == 0){
            #pragma unroll
            for (int c=0;c<8;c++){
                const float inv = 1.f/(ps[c] + 1e-16f);
                agg [(size_t)d*128 + c*16 + m] = accA[c];
                gacc[(size_t)d*128 + c*16 + m] = accG[c]*inv;
            }
        }
    }
}

// ---------------- k4: MFMA final node kernel ----------------
#define K4N 32
__global__ __launch_bounds__(256) void k4_final(
    const float* __restrict__ x, const float* __restrict__ agg, const float* __restrict__ gacc,
    const float* __restrict__ gat_b, const float* __restrict__ eps_p,
    const unsigned* __restrict__ W1p, const float* __restrict__ b1,
    const unsigned* __restrict__ W2p, const float* __restrict__ gb2,
    const unsigned* __restrict__ combp, const float* __restrict__ comb_b,
    const float* __restrict__ ln_g, const float* __restrict__ ln_b,
    float* __restrict__ out)
{
    __shared__ _Float16 sHi[K4N][136];
    __shared__ _Float16 sLo[K4N][136];
    __shared__ _Float16 sCH[K4N][264];
    __shared__ float sRed[K4N][8];
    __shared__ float sMV[K4N][2];
    const int t = threadIdx.x;
    const int l = t & 63, wid = t >> 6;
    const int n = l & 15, g = l >> 4;
    const float epsv = 1.f + eps_p[0];
    const int base = blockIdx.x*K4N;

    for (int i = t; i < K4N*32; i += 256){
        const int node = i >> 5, c4 = i & 31;
        float4 xv = ((const float4*)x   )[(size_t)(base+node)*32 + c4];
        float4 av = ((const float4*)agg )[(size_t)(base+node)*32 + c4];
        float4 gv = ((const float4*)gacc)[(size_t)(base+node)*32 + c4];
        float4 bv = ((const float4*)gat_b)[c4];
        float h0 = epsv*xv.x + av.x, h1 = epsv*xv.y + av.y;
        float h2_ = epsv*xv.z + av.z, h3 = epsv*xv.w + av.w;
        _Float16 f0=(_Float16)h0, f1=(_Float16)h1, f2=(_Float16)h2_, f3=(_Float16)h3;
        h2v p01; p01.x=f0; p01.y=f1;  h2v p23; p23.x=f2; p23.y=f3;
        *(uint2*)&sHi[node][c4*4] = make_uint2(__builtin_bit_cast(unsigned,p01),
                                               __builtin_bit_cast(unsigned,p23));
        h2v q01, q23;
        q01.x=(_Float16)(h0-(float)f0); q01.y=(_Float16)(h1-(float)f1);
        q23.x=(_Float16)(h2_-(float)f2); q23.y=(_Float16)(h3-(float)f3);
        *(uint2*)&sLo[node][c4*4] = make_uint2(__builtin_bit_cast(unsigned,q01),
                                               __builtin_bit_cast(unsigned,q23));
        *(uint2*)&sCH[node][c4*4] = make_uint2(packh2(gv.x+bv.x, gv.y+bv.y),
                                               packh2(gv.z+bv.z, gv.w+bv.w));
    }
    __syncthreads();

    f32x4v acc1[2][2];
    #pragma unroll
    for (int mt=0;mt<2;mt++)
        #pragma unroll
        for (int nt=0;nt<2;nt++){
            float b = b1[32*wid + 16*nt + n];
            acc1[mt][nt] = (f32x4v){b,b,b,b};
        }
    #pragma unroll
    for (int ks=0;ks<4;ks++){
        h16x8 bfr[2];
        #pragma unroll
        for (int nt=0;nt<2;nt++){
            uint4 u = ((const uint4*)W1p)[(size_t)((ks*8 + 2*wid + nt)*64 + l)];
            bfr[nt] = __builtin_bit_cast(h16x8, u);
        }
        #pragma unroll
        for (int mt=0;mt<2;mt++){
            const int row = 16*mt + n;
            h16x8 ahi = *(const h16x8*)&sHi[row][8*g + 32*ks];
            h16x8 alo = *(const h16x8*)&sLo[row][8*g + 32*ks];
            #pragma unroll
            for (int nt=0;nt<2;nt++){
                acc1[mt][nt] = __builtin_amdgcn_mfma_f32_16x16x32_f16(ahi, bfr[nt], acc1[mt][nt], 0,0,0);
                acc1[mt][nt] = __builtin_amdgcn_mfma_f32_16x16x32_f16(alo, bfr[nt], acc1[mt][nt], 0,0,0);
            }
        }
    }
    __syncthreads();
    #pragma unroll
    for (int mt=0;mt<2;mt++)
        #pragma unroll
        for (int nt=0;nt<2;nt++)
            #pragma unroll
            for (int r=0;r<4;r++)
                sHi[16*mt + 4*g + r][32*wid + 16*nt + n] = (_Float16)fmaxf(acc1[mt][nt][r], 0.f);
    __syncthreads();

    f32x4v acc2[2][2];
    #pragma unroll
    for (int mt=0;mt<2;mt++)
        #pragma unroll
        for (int nt=0;nt<2;nt++){
            float b = gb2[32*wid + 16*nt + n];
            acc2[mt][nt] = (f32x4v){b,b,b,b};
        }
    #pragma unroll
    for (int ks=0;ks<4;ks++){
        h16x8 bfr[2];
        #pragma unroll
        for (int nt=0;nt<2;nt++){
            uint4 u = ((const uint4*)W2p)[(size_t)((ks*8 + 2*wid + nt)*64 + l)];
            bfr[nt] = __builtin_bit_cast(h16x8, u);
        }
        #pragma unroll
        for (int mt=0;mt<2;mt++){
            h16x8 a = *(const h16x8*)&sHi[16*mt + n][8*g + 32*ks];
            #pragma unroll
            for (int nt=0;nt<2;nt++)
                acc2[mt][nt] = __builtin_amdgcn_mfma_f32_16x16x32_f16(a, bfr[nt], acc2[mt][nt], 0,0,0);
        }
    }
    #pragma unroll
    for (int mt=0;mt<2;mt++)
        #pragma unroll
        for (int nt=0;nt<2;nt++)
            #pragma unroll
            for (int r=0;r<4;r++)
                sCH[16*mt + 4*g + r][128 + 32*wid + 16*nt + n] = (_Float16)acc2[mt][nt][r];
    __syncthreads();

    f32x4v accC[2][4];
    #pragma unroll
    for (int mt=0;mt<2;mt++)
        #pragma unroll
        for (int nt=0;nt<4;nt++){
            float b = comb_b[64*wid + 16*nt + n];
            accC[mt][nt] = (f32x4v){b,b,b,b};
        }
    #pragma unroll
    for (int ks=0;ks<8;ks++){
        h16x8 bfr[4];
        #pragma unroll
        for (int nt=0;nt<4;nt++){
            uint4 u = ((const uint4*)combp)[(size_t)((ks*16 + 4*wid + nt)*64 + l)];
            bfr[nt] = __builtin_bit_cast(h16x8, u);
        }
        #pragma unroll
        for (int mt=0;mt<2;mt++){
            h16x8 a = *(const h16x8*)&sCH[16*mt + n][8*g + 32*ks];
            #pragma unroll
            for (int nt=0;nt<4;nt++)
                accC[mt][nt] = __builtin_amdgcn_mfma_f32_16x16x32_f16(a, bfr[nt], accC[mt][nt], 0,0,0);
        }
    }

    #pragma unroll
    for (int mt=0;mt<2;mt++)
        #pragma unroll
        for (int r=0;r<4;r++){
            float s1=0.f, s2=0.f;
            #pragma unroll
            for (int nt=0;nt<4;nt++){ float z = accC[mt][nt][r]; s1 += z; s2 += z*z; }
            #pragma unroll
            for (int off=1; off<16; off<<=1){ s1 += __shfl_xor(s1,off,16); s2 += __shfl_xor(s2,off,16); }
            if (n==0){
                sRed[16*mt + 4*g + r][2*wid  ] = s1;
                sRed[16*mt + 4*g + r][2*wid+1] = s2;
            }
        }
    __syncthreads();
    if (t < K4N){
        float a1 = sRed[t][0]+sRed[t][2]+sRed[t][4]+sRed[t][6];
        float a2 = sRed[t][1]+sRed[t][3]+sRed[t][5]+sRed[t][7];
        float mu = a1*(1.f/256.f);
        float var = a2*(1.f/256.f) - mu*mu;
        sMV[t][0] = mu; sMV[t][1] = rsqrtf(var + 1e-5f);
    }
    __syncthreads();
    float lg[4], lb[4];
    #pragma unroll
    for (int nt=0;nt<4;nt++){ int ch = 64*wid + 16*nt + n; lg[nt]=ln_g[ch]; lb[nt]=ln_b[ch]; }
    #pragma unroll
    for (int mt=0;mt<2;mt++)
        #pragma unroll
        for (int r=0;r<4;r++){
            const int row = 16*mt + 4*g + r;
            const float mu = sMV[row][0], rs = sMV[row][1];
            #pragma unroll
            for (int nt=0;nt<4;nt++){
                const int ch = 64*wid + 16*nt + n;
                float zz = accC[mt][nt][r];
                out[(size_t)(base+row)*256 + ch] = fmaxf((zz-mu)*rs*lg[nt] + lb[nt], 0.f);
            }
        }
}

extern "C" void kernel_launch(void* const* d_in, const int* in_sizes, int n_in,
                              void* d_out, int out_size, void* d_ws, size_t ws_size,
                              hipStream_t stream)
{
    (void)in_sizes; (void)n_in; (void)out_size; (void)ws_size;
    const float* x           = (const float*)d_in[0];
    const int*   eidx_w      = (const int*)  d_in[1];
    const float* eattr       = (const float*)d_in[2];
    const int*   ety_w       = (const int*)  d_in[3];
    const float* gat_W       = (const float*)d_in[4];
    const float* gat_b       = (const float*)d_in[5];
    const float* gat_edge_W  = (const float*)d_in[6];
    const float* a_src       = (const float*)d_in[7];
    const float* a_dst       = (const float*)d_in[8];
    const float* a_edge      = (const float*)d_in[9];
    const float* gat_emb     = (const float*)d_in[10];
    const float* gine_emb    = (const float*)d_in[11];
    const float* gine_edge_W = (const float*)d_in[12];
    const float* gine_edge_b = (const float*)d_in[13];
    const float* gine_eps    = (const float*)d_in[14];
    const float* W1          = (const float*)d_in[15];
    const float* b1          = (const float*)d_in[16];
    const float* W2          = (const float*)d_in[17];
    const float* gb2         = (const float*)d_in[18];
    const float* comb_W      = (const float*)d_in[19];
    const float* comb_b      = (const float*)d_in[20];
    const float* ln_g        = (const float*)d_in[21];
    const float* ln_b        = (const float*)d_in[22];
    float* out = (float*)d_out;

    char* ws = (char*)d_ws;
    size_t off = 0;
    auto alloc = [&](size_t bytes)->void*{ void* p = ws + off; off += (bytes + 255)/256*256; return p; };
    size_t zero_start = off;
    int*      flags  = (int*)     alloc(256);
    int*      cnt    = (int*)     alloc((size_t)N_NODES*4);
    size_t zero_bytes = off - zero_start;
    int*      dstA   = (int*)     alloc((size_t)N_EDGES*4);
    int*      styA   = (int*)     alloc((size_t)N_EDGES*4);
    int*      rankA  = (int*)     alloc((size_t)N_EDGES*4);
    int*      rowp   = (int*)     alloc((size_t)(N_NODES+1)*4);
    unsigned* erec   = (unsigned*)alloc((size_t)N_EDGES*128);
    unsigned* xhb    = (unsigned*)alloc((size_t)N_NODES*128*4);
    float*    a_s    = (float*)   alloc((size_t)N_NODES*8*4);
    float*    a_d    = (float*)   alloc((size_t)N_NODES*8*4);
    float*    Mt     = (float*)   alloc(32*8*4);
    float*    ATw    = (float*)   alloc(16*8*4);
    float*    Tw     = (float*)   alloc(16*128*4);
    float*    agg    = (float*)   alloc((size_t)N_NODES*128*4);
    float*    gacc   = (float*)   alloc((size_t)N_NODES*128*4);
    unsigned* W1p    = (unsigned*)alloc((size_t)32*1024);
    unsigned* W2p    = (unsigned*)alloc((size_t)32*1024);
    unsigned* combp  = (unsigned*)alloc((size_t)128*1024);
    unsigned* Wgp    = (unsigned*)alloc((size_t)32*1024);

    int n4 = (int)(zero_bytes/16);
    k0_zero<<<(n4+255)/256, 256, 0, stream>>>((float4*)(ws + zero_start), n4);
    kD_detect<<<512, 256, 0, stream>>>(eidx_w, ety_w, flags);
    kN_norm<<<1024, 256, 0, stream>>>(eidx_w, ety_w, flags, dstA, styA, rankA, cnt);
    kS_scan<<<1, 1024, 0, stream>>>(cnt, rowp);

    kW_pack<<<56, 256, 0, stream>>>(W1, W2, comb_W, gat_W, W1p, W2p, combp, Wgp);
    kPre<<<17, 256, 0, stream>>>(gat_edge_W, a_edge, gat_emb, gine_emb,
                                 gine_edge_W, gine_edge_b, Mt, ATw, Tw);
    k1_node_prep<<<N_NODES/K1N, 256, 0, stream>>>(x, Wgp, a_src, a_dst, xhb, a_s, a_d);

    kCE_edge<<<2500, 256, 0, stream>>>(eattr, dstA, styA, rankA, rowp,
                                       a_s, a_d, Mt, ATw, gine_emb, erec);

    k3_gather<<<2500, 256, 0, stream>>>(xhb, erec, rowp,
                                        gine_edge_b, gine_edge_W, agg, gacc);

    k4_final<<<N_NODES/K4N, 256, 0, stream>>>(x, agg, gacc, gat_b, gine_eps,
                                              W1p, b1, W2p, gb2, combp, comb_b,
                                              ln_g, ln_b, out);
}